// Round 10
// baseline (363.293 us; speedup 1.0000x reference)
//
#include <hip/hip_runtime.h>

// ---------------------------------------------------------------------------
// MultiheadSelfAttention: B=2, S=2048, D=1024, H=16, DK=64
// cast->bf16 ; fused QKV GEMM (BK=32 double-buffered pipeline, R7-proven) ;
// flash attention (8-wave block: 2x2x2 qg/kg/SG split — two wave-groups each
// own half the KEY RANGE with private double-buffered LDS, 16 barrier-iters,
// two q-halves sharing K/V frags, no-max exp2 softmax, PV via full-rate K=32
// MFMA, lgkm-only barrier, 4-partial cross-wave reduce) ; output projection.
// R8 lesson: per-wave live state must stay at the R7 level (spill tripwire).
// ---------------------------------------------------------------------------

typedef __attribute__((ext_vector_type(8))) short bf16x8;   // 8 bf16
typedef __attribute__((ext_vector_type(4))) short bf16x4;   // 4 bf16
typedef __attribute__((ext_vector_type(4))) float f32x4;
typedef __attribute__((ext_vector_type(2))) unsigned int u32x2;
typedef __attribute__((ext_vector_type(4))) unsigned int u32x4;

#define GK 1024
#define SEQ 2048
#define NHEAD 16
#define DKD 64
#define PADW 72      // padded LDS row stride (elems) for attn/epilogue tiles

#define MFMA32(a, b, c) __builtin_amdgcn_mfma_f32_16x16x32_bf16((a), (b), (c), 0, 0, 0)

#if __has_builtin(__builtin_amdgcn_exp2f)
#define EXP2(x) __builtin_amdgcn_exp2f(x)
#else
#define EXP2(x) exp2f(x)
#endif

// Q scale: (1/sqrt(64)) * log2(e), folded into the Q projection epilogue
#define QSCALE 0.18033688011f

static __device__ __forceinline__ unsigned short f2bf(float f) {
    unsigned int u = __float_as_uint(f);
    u += 0x7fffu + ((u >> 16) & 1u);     // RNE
    return (unsigned short)(u >> 16);
}

// pack two f32 -> two bf16 in one dword (a -> low half). round-half-up + v_perm.
static __device__ __forceinline__ unsigned int pack_bf2(float a, float b) {
    unsigned int ua = __float_as_uint(a) + 0x8000u;
    unsigned int ub = __float_as_uint(b) + 0x8000u;
    return __builtin_amdgcn_perm(ub, ua, 0x07060302u);  // [b.hi16, a.hi16]
}

// ---------------------------------------------------------------- fused casts
__global__ __launch_bounds__(256) void cast_all(const float* __restrict__ x,
                                                const float* __restrict__ wq,
                                                const float* __restrict__ wk,
                                                const float* __restrict__ wv,
                                                const float* __restrict__ wo,
                                                unsigned short* __restrict__ Xb,
                                                unsigned short* __restrict__ Wqkv,
                                                unsigned short* __restrict__ Wob) {
    const int bid = blockIdx.x;
    const float* src; unsigned short* dst; int off;
    if (bid < 4096)      { src = x;  dst = Xb;             off = bid; }
    else if (bid < 5120) { src = wq; dst = Wqkv;           off = bid - 4096; }
    else if (bid < 6144) { src = wk; dst = Wqkv + 1048576; off = bid - 5120; }
    else if (bid < 7168) { src = wv; dst = Wqkv + 2097152; off = bid - 6144; }
    else                 { src = wo; dst = Wob;            off = bid - 7168; }
    const int i = off * 1024 + threadIdx.x * 4;
    float4 v = *(const float4*)(src + i);
    u32x2 p; p.x = pack_bf2(v.x, v.y); p.y = pack_bf2(v.z, v.w);
    *(u32x2*)(dst + i) = p;
}

// ---------------------------------------------------------------- GEMM C = A * B^T
// R7-PROVEN BK=32 DOUBLE-BUFFERED K-loop (32 steps, ONE barrier each):
//   barrier -> issue global_load_lds for tile k+1 into the other buffer
//           -> ds_read frags + 16 MFMA on tile k.
// The barrier's vmcnt(0) drain waits for loads issued one full compute-phase
// earlier (latency hidden). Rows are 4 x 16B chunks, XOR-swizzled: LDS chunk
// c' of row r holds global chunk c'^(r&3) (per-lane GLOBAL address permuted;
// LDS dest stays uniform+lane*16B as global_load_lds requires). MODE 0: QKV
// epilogue via per-wave LDS scratch UNIONED with the loop buffers. MODE 1:
// fp32 +bias. (R9's counted-vmcnt triple-buffer measured neutral; reverted.)
template <int MODE, int BN>
__global__ __launch_bounds__(256) void gemm_bt(const unsigned short* __restrict__ A,
                                               const unsigned short* __restrict__ Bw,
                                               unsigned short* __restrict__ outb,
                                               float* __restrict__ outf,
                                               const float* __restrict__ bias) {
    constexpr int NJ = BN / 32;
    constexpr int TILE = (128 + BN) * 32;            // elems per buffer (A then B)
    constexpr int LOOP_BYTES = 2 * TILE * 2;         // double-buffered
    constexpr int EPI_BYTES  = 4 * 64 * PADW * 2;
    constexpr int SMEM_BYTES = (MODE == 0)
        ? (LOOP_BYTES > EPI_BYTES ? LOOP_BYTES : EPI_BYTES)
        : LOOP_BYTES;
    __shared__ __align__(16) unsigned char SMEM[SMEM_BYTES];
    unsigned short* Buf0 = (unsigned short*)SMEM;    // A[128][32] + B[BN][32], swizzled
    unsigned short* Buf1 = Buf0 + TILE;

    const int t    = threadIdx.x;
    const int lane = t & 63;
    const int w    = t >> 6;
    const int wm   = (w >> 1) * 64;
    const int wn   = (w & 1) * (BN / 2);
    const int bm0  = blockIdx.x * 128;
    const int bn0  = blockIdx.y * BN;
    const int lm   = lane & 15;
    const int lq   = lane >> 4;
    const int swz  = (lq ^ (lm & 3)) * 8;   // un-swizzled chunk offset (elems)

    const unsigned short* Ab = A + (size_t)bm0 * GK;
    const unsigned short* Bb = Bw + (size_t)bn0 * GK;

    f32x4 acc[4][NJ];
    const f32x4 Z4 = {0.f, 0.f, 0.f, 0.f};
#pragma unroll
    for (int i = 0; i < 4; i++)
#pragma unroll
        for (int j = 0; j < NJ; j++) acc[i][j] = Z4;

    const int q_uni = (t & ~63);

    // stage one BK=32 tile (A + B) into buffer Bp, async via global_load_lds
    auto STAGE = [&](unsigned short* Bp, int k0) {
        // A: 128 rows x 4 chunks = 512 chunks, 2 per thread
#pragma unroll
        for (int i = 0; i < 2; ++i) {
            int q  = i * 256 + t;
            int r  = q >> 2;
            int gc = (q & 3) ^ (r & 3);          // global col chunk (swizzle)
            int q0 = i * 256 + q_uni;
            __builtin_amdgcn_global_load_lds(
                (const __attribute__((address_space(1))) void*)(Ab + (size_t)r * GK + k0 + gc * 8),
                (__attribute__((address_space(3))) void*)(Bp + (size_t)q0 * 8),
                16, 0, 0);
        }
        // B: BN rows x 4 chunks, BN/64 per thread
#pragma unroll
        for (int i = 0; i < BN / 64; ++i) {
            int q  = i * 256 + t;
            int r  = q >> 2;
            int gc = (q & 3) ^ (r & 3);
            int q0 = i * 256 + q_uni;
            __builtin_amdgcn_global_load_lds(
                (const __attribute__((address_space(1))) void*)(Bb + (size_t)r * GK + k0 + gc * 8),
                (__attribute__((address_space(3))) void*)(Bp + 128 * 32 + (size_t)q0 * 8),
                16, 0, 0);
        }
    };

    STAGE(Buf0, 0);                          // prologue: tile 0 in flight
    for (int ks = 0; ks < GK / 32; ++ks) {
        __syncthreads();                     // tile ks landed; prev reads retired
        unsigned short* Cur = (ks & 1) ? Buf1 : Buf0;
        unsigned short* Nxt = (ks & 1) ? Buf0 : Buf1;
        if (ks + 1 < GK / 32) STAGE(Nxt, (ks + 1) * 32);  // async, hides under compute

        bf16x8 af[4], bf[NJ];
#pragma unroll
        for (int i = 0; i < 4; i++)
            af[i] = *(const bf16x8*)(Cur + (wm + i * 16 + lm) * 32 + swz);
#pragma unroll
        for (int j = 0; j < NJ; j++)
            bf[j] = *(const bf16x8*)(Cur + 128 * 32 + (wn + j * 16 + lm) * 32 + swz);
#pragma unroll
        for (int i = 0; i < 4; i++)
#pragma unroll
            for (int j = 0; j < NJ; j++)
                acc[i][j] = MFMA32(af[i], bf[j], acc[i][j]);
    }

    if (MODE == 0) {
        __syncthreads();                         // all K-loop LDS reads retired
        unsigned short* E  = (unsigned short*)SMEM;   // union with loop buffers
        unsigned short* Ew = E + w * (64 * PADW);
        const int nbase = bn0 + wn;
        const int which = nbase >> 10;            // 0=Q 1=K 2=V
        const int hh    = (nbase & 1023) >> 6;
        const int lq4   = lq * 4;
        if (which != 2) {
            const float sc = (which == 0) ? QSCALE : 1.0f;
#pragma unroll
            for (int i = 0; i < 4; i++)
#pragma unroll
                for (int j = 0; j < 4; j++)
#pragma unroll
                    for (int r = 0; r < 4; r++)
                        Ew[(i * 16 + lq4 + r) * PADW + j * 16 + lm] =
                            f2bf(acc[i][j][r] * sc);
            unsigned short* dst = outb + (size_t)which * 4194304;
#pragma unroll
            for (int rep = 0; rep < 8; ++rep) {
                const int mm = rep * 8 + (lane >> 3);
                const int d0 = (lane & 7) * 8;
                uint4 v = *(const uint4*)(Ew + mm * PADW + d0);
                const int m_g = bm0 + wm + mm;
                const int b = m_g >> 11, s = m_g & 2047;
                *(uint4*)(dst + (((size_t)(b * NHEAD + hh)) * SEQ + s) * DKD + d0) = v;
            }
        } else {
#pragma unroll
            for (int i = 0; i < 4; i++)
#pragma unroll
                for (int j = 0; j < 4; j++) {
                    u32x2 pk;
                    pk.x = pack_bf2(acc[i][j][0], acc[i][j][1]);
                    pk.y = pack_bf2(acc[i][j][2], acc[i][j][3]);
                    *(u32x2*)(Ew + (j * 16 + lm) * PADW + i * 16 + lq4) = pk;
                }
            unsigned short* dst = outb + (size_t)2 * 4194304;
#pragma unroll
            for (int rep = 0; rep < 8; ++rep) {
                const int nn = rep * 8 + (lane >> 3);
                const int mc = (lane & 7) * 8;
                uint4 v = *(const uint4*)(Ew + nn * PADW + mc);
                const int m_g = bm0 + wm + mc;
                const int b = m_g >> 11, s0 = m_g & 2047;
                *(uint4*)(dst + (((size_t)(b * NHEAD + hh)) * DKD + nn) * SEQ + s0) = v;
            }
        }
    } else {
#pragma unroll
        for (int i = 0; i < 4; i++) {
            const int mbase = bm0 + wm + i * 16 + lq * 4;
#pragma unroll
            for (int j = 0; j < NJ; j++) {
                const int n = bn0 + wn + j * 16 + lm;
#pragma unroll
                for (int r = 0; r < 4; r++)
                    outf[(size_t)(mbase + r) * 1024 + n] = acc[i][j][r] + bias[n];
            }
        }
    }
}

// ---------------------------------------------------------------- flash attention
// 8-WAVE BLOCK, 2x2x2 SPLIT: block = 128 q rows (two 64-row halves), 512
// threads. Wave w: sg = w>>2 (KEY-RANGE group: sg*1024..+1023), qg = (w&3)>>1
// (32 q rows within each half), kg = w&1 (32 keys of each 64-key tile).
// Each sg-group has a PRIVATE double-buffered K/V LDS slice and stages its
// own tiles (per-thread staging identical to the R7 256-thread pattern);
// both groups march the same 16-iteration loop under the block barrier.
// Per-wave loop body and live state are EXACTLY R7's (VGPR ~100, no spill):
// 2 q-halves share ak/bv; PV at full K=32 (k-permutation f(kq*8+kc*4+r) =
// kc*16+kq*4+r applied identically to P pack order and V reads -> exact).
// vs R7: barrier-iterations 32 -> 16, waves/SIMD 2 -> 4, same total work.
// lgkm-only barrier (LDS ordering suffices; global prefetch stays in flight).
// Epilogue: 4-partial (2 kg x 2 sg) reduce through the retired 72KB loop LDS
// (512 rows x 36 floats = 18,432 = exact fit). LDS 73,728 B -> 2 blocks/CU;
// grid 512 = 8 XCD x 4 heads x 16 q-super-blocks, exactly resident.
__global__ __launch_bounds__(512, 4) void attn_kernel(const unsigned short* __restrict__ Qg,
                                                      const unsigned short* __restrict__ Kg,
                                                      const unsigned short* __restrict__ Vtg,
                                                      unsigned short* __restrict__ Og) {
    __shared__ __align__(16) unsigned short KV[2][2][2][64 * PADW];  // [sg][buf][K/V] 73,728 B

    const int id  = blockIdx.x;
    const int xcd = id & 7;
    const int j8  = id >> 3;                 // 0..63
    const int bh  = xcd * 4 + (j8 & 3);      // 4 heads per XCD
    const int qb  = j8 >> 2;                 // 0..15 (128-row q super-blocks)
    const unsigned short* Qp  = Qg  + ((size_t)bh * SEQ + qb * 128) * DKD;
    const unsigned short* Kp  = Kg  + (size_t)bh * SEQ * DKD;
    const unsigned short* Vtp = Vtg + (size_t)bh * DKD * SEQ;

    const int t    = threadIdx.x;            // 0..511
    const int lane = t & 63;
    const int w    = t >> 6;                 // 0..7
    const int sg   = w >> 2;                 // key-range group (1024 keys)
    const int qg   = (w & 3) >> 1;           // q-group (32 rows within each half)
    const int kg   = w & 1;                  // key-group (32 keys of each 64-key tile)
    const int lm   = lane & 15;
    const int kq   = lane >> 4;

    const f32x4 Z4 = {0.f, 0.f, 0.f, 0.f};

    // Q B-frags: two 64-row halves, this wave's 32 rows of each
    bf16x8 aq[2][2][2];            // [half][c][kk]
#pragma unroll
    for (int h2 = 0; h2 < 2; ++h2)
#pragma unroll
        for (int c = 0; c < 2; ++c)
#pragma unroll
            for (int kk = 0; kk < 2; ++kk)
                aq[h2][c][kk] = *(const bf16x8*)(Qp + (size_t)(h2 * 64 + qg * 32 + c * 16 + lm) * DKD + kk * 32 + kq * 8);

    f32x4 o[2][2][4];              // [half][q-chunk][d-chunk], partial over 32 keys x 16 tiles
    float ls[2][2];                // [half][q-chunk] in-lane l partial
#pragma unroll
    for (int h2 = 0; h2 < 2; ++h2)
#pragma unroll
        for (int c = 0; c < 2; ++c) {
            ls[h2][c] = 0.f;
#pragma unroll
            for (int dj = 0; dj < 4; ++dj) o[h2][c][dj] = Z4;
        }

    // staging: per sg-group (256 threads), K tile [64 key][64 d], V tile
    // [64 d][64 key]; 2 uint4/thread each — identical per-thread shape to R7.
    const int tl = t & 255;
    const int sr = tl >> 2, sc = (tl & 3) * 16;
    const unsigned short* KpW = Kp + (size_t)(sg * 1024 + sr) * DKD + sc;
    const unsigned short* VpW = Vtp + (size_t)sr * SEQ + sg * 1024 + sc;
    uint4 kreg0, kreg1, vreg0, vreg1;
    {   // tile 0 -> buf 0
        uint4 a0 = *(const uint4*)(KpW), a1 = *(const uint4*)(KpW + 8);
        uint4 b0 = *(const uint4*)(VpW), b1 = *(const uint4*)(VpW + 8);
        uint4* dk = (uint4*)(&KV[sg][0][0][sr * PADW + sc]); dk[0] = a0; dk[1] = a1;
        uint4* dv = (uint4*)(&KV[sg][0][1][sr * PADW + sc]); dv[0] = b0; dv[1] = b1;
    }
    {   // prefetch tile 1
        kreg0 = *(const uint4*)(KpW + 64 * DKD); kreg1 = *(const uint4*)(KpW + 64 * DKD + 8);
        vreg0 = *(const uint4*)(VpW + 64);       vreg1 = *(const uint4*)(VpW + 64 + 8);
    }

    for (int kt = 0; kt < 16; ++kt) {
        // lgkm-only barrier: LDS ordering only; global prefetch stays in flight
        asm volatile("s_waitcnt lgkmcnt(0)\n\ts_barrier" ::: "memory");
        const unsigned short* Kc = &KV[sg][kt & 1][0][0];
        const unsigned short* Vc = &KV[sg][kt & 1][1][0];

        // K A-frags for this wave's 32 keys (issued first; in-order lgkm)
        bf16x8 ak[2][2];
#pragma unroll
        for (int kc = 0; kc < 2; ++kc)
#pragma unroll
            for (int kk = 0; kk < 2; ++kk)
                ak[kc][kk] = *(const bf16x8*)(Kc + (kg * 32 + kc * 16 + lm) * PADW + kk * 32 + kq * 8);

        // write prefetched tile kt+1 -> other buf (its readers retired pre-barrier)
        if (kt + 1 < 16) {
            uint4* dk = (uint4*)(&KV[sg][(kt + 1) & 1][0][sr * PADW + sc]);
            dk[0] = kreg0; dk[1] = kreg1;
            uint4* dv = (uint4*)(&KV[sg][(kt + 1) & 1][1][sr * PADW + sc]);
            dv[0] = vreg0; dv[1] = vreg1;
        }
        if (kt + 2 < 16) {
            const unsigned short* kp = KpW + (size_t)(kt + 2) * 64 * DKD;
            kreg0 = *(const uint4*)(kp); kreg1 = *(const uint4*)(kp + 8);
            const unsigned short* vp = VpW + (kt + 2) * 64;
            vreg0 = *(const uint4*)(vp); vreg1 = *(const uint4*)(vp + 8);
        }

        // V B-frags under permutation f (shared by both q-halves)
        bf16x8 bv[4];
#pragma unroll
        for (int dj = 0; dj < 4; ++dj) {
            const unsigned short* vr = Vc + (dj * 16 + lm) * PADW + kg * 32;
            u32x2 lo = __builtin_bit_cast(u32x2, *(const bf16x4*)(vr + kq * 4));
            u32x2 hi = __builtin_bit_cast(u32x2, *(const bf16x4*)(vr + 16 + kq * 4));
            u32x4 uu; uu.x = lo.x; uu.y = lo.y; uu.z = hi.x; uu.w = hi.y;
            bv[dj] = __builtin_bit_cast(bf16x8, uu);
        }

        // two independent q-halves share ak/bv: 2x work per staged byte
#pragma unroll
        for (int h2 = 0; h2 < 2; ++h2) {
            // S^T[32 keys][32 q]: s[kc][c], lane holds key kc*16+kq*4+r, q c*16+lm
            f32x4 s[2][2];
            __builtin_amdgcn_s_setprio(1);
#pragma unroll
            for (int kc = 0; kc < 2; ++kc)
#pragma unroll
                for (int c = 0; c < 2; ++c) {
                    s[kc][c] = MFMA32(ak[kc][0], aq[h2][c][0], Z4);
                    s[kc][c] = MFMA32(ak[kc][1], aq[h2][c][1], s[kc][c]);
                }
            __builtin_amdgcn_s_setprio(0);

            // p = exp2(s); accumulate in-lane l over both key sub-chunks
#pragma unroll
            for (int c = 0; c < 2; ++c) {
#pragma unroll
                for (int kc = 0; kc < 2; ++kc)
#pragma unroll
                    for (int r = 0; r < 4; ++r) s[kc][c][r] = EXP2(s[kc][c][r]);
                ls[h2][c] += ((s[0][c][0] + s[0][c][1]) + (s[0][c][2] + s[0][c][3]))
                           + ((s[1][c][0] + s[1][c][1]) + (s[1][c][2] + s[1][c][3]));
            }

            // pack P under f: element j=kc*4+r = P[q=lm][key kc*16+kq*4+r]
            bf16x8 pa[2];
#pragma unroll
            for (int c = 0; c < 2; ++c) {
                u32x4 uu;
                uu.x = pack_bf2(s[0][c][0], s[0][c][1]);
                uu.y = pack_bf2(s[0][c][2], s[0][c][3]);
                uu.z = pack_bf2(s[1][c][0], s[1][c][1]);
                uu.w = pack_bf2(s[1][c][2], s[1][c][3]);
                pa[c] = __builtin_bit_cast(bf16x8, uu);
            }

            // O += P V over this wave's 32 keys — full K=32 MFMA
            __builtin_amdgcn_s_setprio(1);
#pragma unroll
            for (int dj = 0; dj < 4; ++dj)
#pragma unroll
                for (int c = 0; c < 2; ++c)
                    o[h2][c][dj] = MFMA32(pa[c], bv[dj], o[h2][c][dj]);
            __builtin_amdgcn_s_setprio(0);
        }
    }

    // ---------------- cross-wave reduction through retired KV LDS ----------
    __syncthreads();
    float* Lf = (float*)(&KV[0][0][0][0]);    // 18,432 floats available

    // l: reduce over kq in-wave, write per-wave partials Lf[(h2*8 + w)*32 + ql]
#pragma unroll
    for (int h2 = 0; h2 < 2; ++h2)
#pragma unroll
        for (int c = 0; c < 2; ++c) {
            float v = ls[h2][c];
            v += __shfl_xor(v, 16);
            v += __shfl_xor(v, 32);
            if (kq == 0) Lf[(h2 * 8 + w) * 32 + c * 16 + lm] = v;
        }
    __syncthreads();

    // reader mapping: 512 threads, 4 d-elems each; rows of partials to sum
    // for (h2, row rq): waves {2qgr, 2qgr+1, 2qgr+4, 2qgr+5} (kg x sg).
    const int rq  = t >> 3;                   // 0..63 (row within half)
    const int dq  = (t & 7) * 4;              // d offset within 32-chunk
    const int qgr = rq >> 5, qlr = rq & 31;
    const int w0  = qgr * 2;
    float li[2];
#pragma unroll
    for (int h2 = 0; h2 < 2; ++h2) {
        float l = (Lf[(h2 * 8 + w0) * 32 + qlr]     + Lf[(h2 * 8 + w0 + 1) * 32 + qlr])
                + (Lf[(h2 * 8 + w0 + 4) * 32 + qlr] + Lf[(h2 * 8 + w0 + 5) * 32 + qlr]);
#if __has_builtin(__builtin_amdgcn_rcpf)
        li[h2] = __builtin_amdgcn_rcpf(l);
#else
        li[h2] = 1.0f / l;
#endif
    }
    __syncthreads();                          // l reads done before overwrite

    const int b = bh >> 4, h = bh & 15;
    // O: two passes of 32 d-columns; 512 partial rows (2 h2 x 8 waves x 32)
    // x 36-float stride = 18,432 floats exactly.
#pragma unroll
    for (int p = 0; p < 2; ++p) {
#pragma unroll
        for (int h2 = 0; h2 < 2; ++h2)
#pragma unroll
            for (int c = 0; c < 2; ++c)
#pragma unroll
                for (int djh = 0; djh < 2; ++djh) {
                    const int dj = 2 * p + djh;
#pragma unroll
                    for (int r = 0; r < 4; ++r)
                        Lf[((h2 * 8 + w) * 32 + c * 16 + kq * 4 + r) * 36 + djh * 16 + lm] = o[h2][c][dj][r];
                }
        __syncthreads();
#pragma unroll
        for (int h2 = 0; h2 < 2; ++h2) {
            f32x4 a = *(const f32x4*)(Lf + ((h2 * 8 + w0) * 32 + qlr) * 36 + dq)
                    + *(const f32x4*)(Lf + ((h2 * 8 + w0 + 1) * 32 + qlr) * 36 + dq)
                    + *(const f32x4*)(Lf + ((h2 * 8 + w0 + 4) * 32 + qlr) * 36 + dq)
                    + *(const f32x4*)(Lf + ((h2 * 8 + w0 + 5) * 32 + qlr) * 36 + dq);
            u32x2 outv;
            outv.x = pack_bf2(a[0] * li[h2], a[1] * li[h2]);
            outv.y = pack_bf2(a[2] * li[h2], a[3] * li[h2]);
            *(u32x2*)(Og + (((size_t)(b * SEQ + qb * 128 + h2 * 64 + rq)) * NHEAD + h) * DKD + p * 32 + dq) = outv;
        }
        __syncthreads();
    }
}

// ---------------------------------------------------------------- launcher
extern "C" void kernel_launch(void* const* d_in, const int* in_sizes, int n_in,
                              void* d_out, int out_size, void* d_ws, size_t ws_size,
                              hipStream_t stream) {
    const float* x  = (const float*)d_in[0];
    const float* Wq = (const float*)d_in[1];
    const float* Wk = (const float*)d_in[2];
    const float* Wv = (const float*)d_in[3];
    const float* Wo = (const float*)d_in[4];
    const float* bo = (const float*)d_in[5];
    float* out = (float*)d_out;

    unsigned short* ws = (unsigned short*)d_ws;
    unsigned short* Xb   = ws;                       // [4096][1024]
    unsigned short* Wqkv = ws + 4194304;             // [3072][1024] (Wq|Wk|Wv)
    unsigned short* Wob  = ws + 7340032;             // [1024][1024]
    unsigned short* QKV  = ws + 8388608;             // Q,K:[b,h,s,d]; V:[b,h,d,s]
    unsigned short* Ob   = ws + 20971520;            // [4096][1024] = [b,s,h,d]

    cast_all<<<8192, 256, 0, stream>>>(x, Wq, Wk, Wv, Wo, Xb, Wqkv, Wob);
    gemm_bt<0, 128><<<dim3(32, 24), 256, 0, stream>>>(Xb, Wqkv, QKV, nullptr, nullptr);
    attn_kernel<<<512, 512, 0, stream>>>(QKV, QKV + 4194304, QKV + 8388608, Ob);
    gemm_bt<1, 64><<<dim3(32, 16), 256, 0, stream>>>(Ob, Wob, nullptr, out, bo);
}

// Round 11
// 179.782 us; speedup vs baseline: 2.0207x; 2.0207x over previous
//
#include <hip/hip_runtime.h>

// ---------------------------------------------------------------------------
// MultiheadSelfAttention: B=2, S=2048, D=1024, H=16, DK=64
// cast->bf16 ; fused QKV GEMM (BK=32 double-buffered pipeline, R7-proven) ;
// flash attention (R7-proven: 128-row Q tile, 2x2 q/key wave split, two
// q-halves sharing K/V frags, KVBLK=64, no-max exp2 softmax, PV via full-rate
// K=32 MFMA, lgkm-only barrier) ; output projection.
// Session envelope (measured): cooperative lockstep staging + ~100 live VGPR
// + 2 blocks/CU + 2x q-ILP is the optimum. Proven regressions outside it:
//  R1 free-run waves (FETCH x6.6), R3 K->reg (spill), R8 KVBLK=128 (spill),
//  R9 counted-vmcnt triple-buffer (neutral), R10 8-wave block (launch_bounds
//  (512,4) => 64-VGPR cap => 1GB scratch traffic).
// ---------------------------------------------------------------------------

typedef __attribute__((ext_vector_type(8))) short bf16x8;   // 8 bf16
typedef __attribute__((ext_vector_type(4))) short bf16x4;   // 4 bf16
typedef __attribute__((ext_vector_type(4))) float f32x4;
typedef __attribute__((ext_vector_type(2))) unsigned int u32x2;
typedef __attribute__((ext_vector_type(4))) unsigned int u32x4;

#define GK 1024
#define SEQ 2048
#define NHEAD 16
#define DKD 64
#define PADW 72      // padded LDS row stride (elems) for attn/epilogue tiles

#define MFMA32(a, b, c) __builtin_amdgcn_mfma_f32_16x16x32_bf16((a), (b), (c), 0, 0, 0)

#if __has_builtin(__builtin_amdgcn_exp2f)
#define EXP2(x) __builtin_amdgcn_exp2f(x)
#else
#define EXP2(x) exp2f(x)
#endif

// Q scale: (1/sqrt(64)) * log2(e), folded into the Q projection epilogue
#define QSCALE 0.18033688011f

static __device__ __forceinline__ unsigned short f2bf(float f) {
    unsigned int u = __float_as_uint(f);
    u += 0x7fffu + ((u >> 16) & 1u);     // RNE
    return (unsigned short)(u >> 16);
}

// pack two f32 -> two bf16 in one dword (a -> low half). round-half-up + v_perm.
static __device__ __forceinline__ unsigned int pack_bf2(float a, float b) {
    unsigned int ua = __float_as_uint(a) + 0x8000u;
    unsigned int ub = __float_as_uint(b) + 0x8000u;
    return __builtin_amdgcn_perm(ub, ua, 0x07060302u);  // [b.hi16, a.hi16]
}

// ---------------------------------------------------------------- fused casts
__global__ __launch_bounds__(256) void cast_all(const float* __restrict__ x,
                                                const float* __restrict__ wq,
                                                const float* __restrict__ wk,
                                                const float* __restrict__ wv,
                                                const float* __restrict__ wo,
                                                unsigned short* __restrict__ Xb,
                                                unsigned short* __restrict__ Wqkv,
                                                unsigned short* __restrict__ Wob) {
    const int bid = blockIdx.x;
    const float* src; unsigned short* dst; int off;
    if (bid < 4096)      { src = x;  dst = Xb;             off = bid; }
    else if (bid < 5120) { src = wq; dst = Wqkv;           off = bid - 4096; }
    else if (bid < 6144) { src = wk; dst = Wqkv + 1048576; off = bid - 5120; }
    else if (bid < 7168) { src = wv; dst = Wqkv + 2097152; off = bid - 6144; }
    else                 { src = wo; dst = Wob;            off = bid - 7168; }
    const int i = off * 1024 + threadIdx.x * 4;
    float4 v = *(const float4*)(src + i);
    u32x2 p; p.x = pack_bf2(v.x, v.y); p.y = pack_bf2(v.z, v.w);
    *(u32x2*)(dst + i) = p;
}

// ---------------------------------------------------------------- GEMM C = A * B^T
// R7-PROVEN BK=32 DOUBLE-BUFFERED K-loop (32 steps, ONE barrier each):
//   barrier -> issue global_load_lds for tile k+1 into the other buffer
//           -> ds_read frags + 16 MFMA on tile k.
// The barrier's vmcnt(0) drain waits for loads issued one full compute-phase
// earlier (latency hidden). Rows are 4 x 16B chunks, XOR-swizzled: LDS chunk
// c' of row r holds global chunk c'^(r&3) (per-lane GLOBAL address permuted;
// LDS dest stays uniform+lane*16B as global_load_lds requires). MODE 0: QKV
// epilogue via per-wave LDS scratch UNIONED with the loop buffers. MODE 1:
// fp32 +bias. (R9's counted-vmcnt triple-buffer measured neutral; reverted.)
template <int MODE, int BN>
__global__ __launch_bounds__(256) void gemm_bt(const unsigned short* __restrict__ A,
                                               const unsigned short* __restrict__ Bw,
                                               unsigned short* __restrict__ outb,
                                               float* __restrict__ outf,
                                               const float* __restrict__ bias) {
    constexpr int NJ = BN / 32;
    constexpr int TILE = (128 + BN) * 32;            // elems per buffer (A then B)
    constexpr int LOOP_BYTES = 2 * TILE * 2;         // double-buffered
    constexpr int EPI_BYTES  = 4 * 64 * PADW * 2;
    constexpr int SMEM_BYTES = (MODE == 0)
        ? (LOOP_BYTES > EPI_BYTES ? LOOP_BYTES : EPI_BYTES)
        : LOOP_BYTES;
    __shared__ __align__(16) unsigned char SMEM[SMEM_BYTES];
    unsigned short* Buf0 = (unsigned short*)SMEM;    // A[128][32] + B[BN][32], swizzled
    unsigned short* Buf1 = Buf0 + TILE;

    const int t    = threadIdx.x;
    const int lane = t & 63;
    const int w    = t >> 6;
    const int wm   = (w >> 1) * 64;
    const int wn   = (w & 1) * (BN / 2);
    const int bm0  = blockIdx.x * 128;
    const int bn0  = blockIdx.y * BN;
    const int lm   = lane & 15;
    const int lq   = lane >> 4;
    const int swz  = (lq ^ (lm & 3)) * 8;   // un-swizzled chunk offset (elems)

    const unsigned short* Ab = A + (size_t)bm0 * GK;
    const unsigned short* Bb = Bw + (size_t)bn0 * GK;

    f32x4 acc[4][NJ];
    const f32x4 Z4 = {0.f, 0.f, 0.f, 0.f};
#pragma unroll
    for (int i = 0; i < 4; i++)
#pragma unroll
        for (int j = 0; j < NJ; j++) acc[i][j] = Z4;

    const int q_uni = (t & ~63);

    // stage one BK=32 tile (A + B) into buffer Bp, async via global_load_lds
    auto STAGE = [&](unsigned short* Bp, int k0) {
        // A: 128 rows x 4 chunks = 512 chunks, 2 per thread
#pragma unroll
        for (int i = 0; i < 2; ++i) {
            int q  = i * 256 + t;
            int r  = q >> 2;
            int gc = (q & 3) ^ (r & 3);          // global col chunk (swizzle)
            int q0 = i * 256 + q_uni;
            __builtin_amdgcn_global_load_lds(
                (const __attribute__((address_space(1))) void*)(Ab + (size_t)r * GK + k0 + gc * 8),
                (__attribute__((address_space(3))) void*)(Bp + (size_t)q0 * 8),
                16, 0, 0);
        }
        // B: BN rows x 4 chunks, BN/64 per thread
#pragma unroll
        for (int i = 0; i < BN / 64; ++i) {
            int q  = i * 256 + t;
            int r  = q >> 2;
            int gc = (q & 3) ^ (r & 3);
            int q0 = i * 256 + q_uni;
            __builtin_amdgcn_global_load_lds(
                (const __attribute__((address_space(1))) void*)(Bb + (size_t)r * GK + k0 + gc * 8),
                (__attribute__((address_space(3))) void*)(Bp + 128 * 32 + (size_t)q0 * 8),
                16, 0, 0);
        }
    };

    STAGE(Buf0, 0);                          // prologue: tile 0 in flight
    for (int ks = 0; ks < GK / 32; ++ks) {
        __syncthreads();                     // tile ks landed; prev reads retired
        unsigned short* Cur = (ks & 1) ? Buf1 : Buf0;
        unsigned short* Nxt = (ks & 1) ? Buf0 : Buf1;
        if (ks + 1 < GK / 32) STAGE(Nxt, (ks + 1) * 32);  // async, hides under compute

        bf16x8 af[4], bf[NJ];
#pragma unroll
        for (int i = 0; i < 4; i++)
            af[i] = *(const bf16x8*)(Cur + (wm + i * 16 + lm) * 32 + swz);
#pragma unroll
        for (int j = 0; j < NJ; j++)
            bf[j] = *(const bf16x8*)(Cur + 128 * 32 + (wn + j * 16 + lm) * 32 + swz);
#pragma unroll
        for (int i = 0; i < 4; i++)
#pragma unroll
            for (int j = 0; j < NJ; j++)
                acc[i][j] = MFMA32(af[i], bf[j], acc[i][j]);
    }

    if (MODE == 0) {
        __syncthreads();                         // all K-loop LDS reads retired
        unsigned short* E  = (unsigned short*)SMEM;   // union with loop buffers
        unsigned short* Ew = E + w * (64 * PADW);
        const int nbase = bn0 + wn;
        const int which = nbase >> 10;            // 0=Q 1=K 2=V
        const int hh    = (nbase & 1023) >> 6;
        const int lq4   = lq * 4;
        if (which != 2) {
            const float sc = (which == 0) ? QSCALE : 1.0f;
#pragma unroll
            for (int i = 0; i < 4; i++)
#pragma unroll
                for (int j = 0; j < 4; j++)
#pragma unroll
                    for (int r = 0; r < 4; r++)
                        Ew[(i * 16 + lq4 + r) * PADW + j * 16 + lm] =
                            f2bf(acc[i][j][r] * sc);
            unsigned short* dst = outb + (size_t)which * 4194304;
#pragma unroll
            for (int rep = 0; rep < 8; ++rep) {
                const int mm = rep * 8 + (lane >> 3);
                const int d0 = (lane & 7) * 8;
                uint4 v = *(const uint4*)(Ew + mm * PADW + d0);
                const int m_g = bm0 + wm + mm;
                const int b = m_g >> 11, s = m_g & 2047;
                *(uint4*)(dst + (((size_t)(b * NHEAD + hh)) * SEQ + s) * DKD + d0) = v;
            }
        } else {
#pragma unroll
            for (int i = 0; i < 4; i++)
#pragma unroll
                for (int j = 0; j < 4; j++) {
                    u32x2 pk;
                    pk.x = pack_bf2(acc[i][j][0], acc[i][j][1]);
                    pk.y = pack_bf2(acc[i][j][2], acc[i][j][3]);
                    *(u32x2*)(Ew + (j * 16 + lm) * PADW + i * 16 + lq4) = pk;
                }
            unsigned short* dst = outb + (size_t)2 * 4194304;
#pragma unroll
            for (int rep = 0; rep < 8; ++rep) {
                const int nn = rep * 8 + (lane >> 3);
                const int mc = (lane & 7) * 8;
                uint4 v = *(const uint4*)(Ew + nn * PADW + mc);
                const int m_g = bm0 + wm + mc;
                const int b = m_g >> 11, s0 = m_g & 2047;
                *(uint4*)(dst + (((size_t)(b * NHEAD + hh)) * DKD + nn) * SEQ + s0) = v;
            }
        }
    } else {
#pragma unroll
        for (int i = 0; i < 4; i++) {
            const int mbase = bm0 + wm + i * 16 + lq * 4;
#pragma unroll
            for (int j = 0; j < NJ; j++) {
                const int n = bn0 + wn + j * 16 + lm;
#pragma unroll
                for (int r = 0; r < 4; r++)
                    outf[(size_t)(mbase + r) * 1024 + n] = acc[i][j][r] + bias[n];
            }
        }
    }
}

// ---------------------------------------------------------------- flash attention
// R7-PROVEN VERSION (49.1 us, VGPR 100, no spill). 128-ROW Q TILE, 2x2 SPLIT:
// block covers 128 q rows as TWO 64-row halves; wave w = (qg = w>>1, kg = w&1)
// owns rows half*64 + qg*32..+31 x keys kg*32..+31 of each 64-key tile. Both
// halves processed per K-tile iteration SHARING the same ak/bv LDS fragments
// and the same cooperative staging -> 2x work per staged byte. PV at full K=32
// depth (k-permutation f(kq*8+kc*4+r) = kc*16+kq*4+r applied identically to P
// pack order and V fragment reads -> exact contraction). K-loop barrier is
// lgkm-only (LDS ordering suffices; global prefetch stays in flight).
// Grid 512 = 8 XCD x 4 heads x 16 q-super-blocks, 2 blocks/CU.
__global__ __launch_bounds__(256, 2) void attn_kernel(const unsigned short* __restrict__ Qg,
                                                      const unsigned short* __restrict__ Kg,
                                                      const unsigned short* __restrict__ Vtg,
                                                      unsigned short* __restrict__ Og) {
    __shared__ __align__(16) unsigned short KV[2][2][64 * PADW];  // 36,864 B

    const int id  = blockIdx.x;
    const int xcd = id & 7;
    const int j8  = id >> 3;                 // 0..63
    const int bh  = xcd * 4 + (j8 & 3);      // 4 heads per XCD
    const int qb  = j8 >> 2;                 // 0..15 (128-row q super-blocks)
    const unsigned short* Qp  = Qg  + ((size_t)bh * SEQ + qb * 128) * DKD;
    const unsigned short* Kp  = Kg  + (size_t)bh * SEQ * DKD;
    const unsigned short* Vtp = Vtg + (size_t)bh * DKD * SEQ;

    const int t    = threadIdx.x;
    const int lane = t & 63;
    const int w    = t >> 6;
    const int qg   = w >> 1;       // q-group (32 rows within each 64-row half)
    const int kg   = w & 1;        // key-group (32 keys of each 64-key tile)
    const int lm   = lane & 15;
    const int kq   = lane >> 4;

    const f32x4 Z4 = {0.f, 0.f, 0.f, 0.f};

    // Q B-frags: two 64-row halves, this wave's 32 rows of each
    bf16x8 aq[2][2][2];            // [half][c][kk]
#pragma unroll
    for (int h2 = 0; h2 < 2; ++h2)
#pragma unroll
        for (int c = 0; c < 2; ++c)
#pragma unroll
            for (int kk = 0; kk < 2; ++kk)
                aq[h2][c][kk] = *(const bf16x8*)(Qp + (size_t)(h2 * 64 + qg * 32 + c * 16 + lm) * DKD + kk * 32 + kq * 8);

    f32x4 o[2][2][4];              // [half][q-chunk][d-chunk], partial over 32 keys
    float ls[2][2];                // [half][q-chunk] in-lane l partial
#pragma unroll
    for (int h2 = 0; h2 < 2; ++h2)
#pragma unroll
        for (int c = 0; c < 2; ++c) {
            ls[h2][c] = 0.f;
#pragma unroll
            for (int dj = 0; dj < 4; ++dj) o[h2][c][dj] = Z4;
        }

    // staging: K tile [64 key][64 d], V tile [64 d][64 key]; 2 uint4/thread each
    const int sr = t >> 2, sc = (t & 3) * 16;
    uint4 kreg0, kreg1, vreg0, vreg1;
    {   // tile 0 -> buf 0
        const unsigned short* kp = Kp + (size_t)sr * DKD + sc;
        const unsigned short* vp = Vtp + (size_t)sr * SEQ + sc;
        uint4 a0 = *(const uint4*)(kp), a1 = *(const uint4*)(kp + 8);
        uint4 b0 = *(const uint4*)(vp), b1 = *(const uint4*)(vp + 8);
        uint4* dk = (uint4*)(&KV[0][0][sr * PADW + sc]); dk[0] = a0; dk[1] = a1;
        uint4* dv = (uint4*)(&KV[0][1][sr * PADW + sc]); dv[0] = b0; dv[1] = b1;
    }
    {   // prefetch tile 1
        const unsigned short* kp = Kp + (size_t)(64 + sr) * DKD + sc;
        kreg0 = *(const uint4*)(kp); kreg1 = *(const uint4*)(kp + 8);
        const unsigned short* vp = Vtp + (size_t)sr * SEQ + 64 + sc;
        vreg0 = *(const uint4*)(vp); vreg1 = *(const uint4*)(vp + 8);
    }

    for (int kt = 0; kt < 32; ++kt) {
        // lgkm-only barrier: LDS ordering only; global prefetch stays in flight
        asm volatile("s_waitcnt lgkmcnt(0)\n\ts_barrier" ::: "memory");
        const unsigned short* Kc = &KV[kt & 1][0][0];
        const unsigned short* Vc = &KV[kt & 1][1][0];

        // K A-frags for this wave's 32 keys (issued first; in-order lgkm)
        bf16x8 ak[2][2];
#pragma unroll
        for (int kc = 0; kc < 2; ++kc)
#pragma unroll
            for (int kk = 0; kk < 2; ++kk)
                ak[kc][kk] = *(const bf16x8*)(Kc + (kg * 32 + kc * 16 + lm) * PADW + kk * 32 + kq * 8);

        // write prefetched tile kt+1 -> other buf (its readers retired pre-barrier)
        if (kt + 1 < 32) {
            uint4* dk = (uint4*)(&KV[(kt + 1) & 1][0][sr * PADW + sc]);
            dk[0] = kreg0; dk[1] = kreg1;
            uint4* dv = (uint4*)(&KV[(kt + 1) & 1][1][sr * PADW + sc]);
            dv[0] = vreg0; dv[1] = vreg1;
        }
        if (kt + 2 < 32) {
            const unsigned short* kp = Kp + (size_t)((kt + 2) * 64 + sr) * DKD + sc;
            kreg0 = *(const uint4*)(kp); kreg1 = *(const uint4*)(kp + 8);
            const unsigned short* vp = Vtp + (size_t)sr * SEQ + (kt + 2) * 64 + sc;
            vreg0 = *(const uint4*)(vp); vreg1 = *(const uint4*)(vp + 8);
        }

        // V B-frags under permutation f (shared by both q-halves)
        bf16x8 bv[4];
#pragma unroll
        for (int dj = 0; dj < 4; ++dj) {
            const unsigned short* vr = Vc + (dj * 16 + lm) * PADW + kg * 32;
            u32x2 lo = __builtin_bit_cast(u32x2, *(const bf16x4*)(vr + kq * 4));
            u32x2 hi = __builtin_bit_cast(u32x2, *(const bf16x4*)(vr + 16 + kq * 4));
            u32x4 uu; uu.x = lo.x; uu.y = lo.y; uu.z = hi.x; uu.w = hi.y;
            bv[dj] = __builtin_bit_cast(bf16x8, uu);
        }

        // two independent q-halves share ak/bv: 2x work per staged byte
#pragma unroll
        for (int h2 = 0; h2 < 2; ++h2) {
            // S^T[32 keys][32 q]: s[kc][c], lane holds key kc*16+kq*4+r, q c*16+lm
            f32x4 s[2][2];
            __builtin_amdgcn_s_setprio(1);
#pragma unroll
            for (int kc = 0; kc < 2; ++kc)
#pragma unroll
                for (int c = 0; c < 2; ++c) {
                    s[kc][c] = MFMA32(ak[kc][0], aq[h2][c][0], Z4);
                    s[kc][c] = MFMA32(ak[kc][1], aq[h2][c][1], s[kc][c]);
                }
            __builtin_amdgcn_s_setprio(0);

            // p = exp2(s); accumulate in-lane l over both key sub-chunks
#pragma unroll
            for (int c = 0; c < 2; ++c) {
#pragma unroll
                for (int kc = 0; kc < 2; ++kc)
#pragma unroll
                    for (int r = 0; r < 4; ++r) s[kc][c][r] = EXP2(s[kc][c][r]);
                ls[h2][c] += ((s[0][c][0] + s[0][c][1]) + (s[0][c][2] + s[0][c][3]))
                           + ((s[1][c][0] + s[1][c][1]) + (s[1][c][2] + s[1][c][3]));
            }

            // pack P under f: element j=kc*4+r = P[q=lm][key kc*16+kq*4+r]
            bf16x8 pa[2];
#pragma unroll
            for (int c = 0; c < 2; ++c) {
                u32x4 uu;
                uu.x = pack_bf2(s[0][c][0], s[0][c][1]);
                uu.y = pack_bf2(s[0][c][2], s[0][c][3]);
                uu.z = pack_bf2(s[1][c][0], s[1][c][1]);
                uu.w = pack_bf2(s[1][c][2], s[1][c][3]);
                pa[c] = __builtin_bit_cast(bf16x8, uu);
            }

            // O += P V over this wave's 32 keys — full K=32 MFMA
            __builtin_amdgcn_s_setprio(1);
#pragma unroll
            for (int dj = 0; dj < 4; ++dj)
#pragma unroll
                for (int c = 0; c < 2; ++c)
                    o[h2][c][dj] = MFMA32(pa[c], bv[dj], o[h2][c][dj]);
            __builtin_amdgcn_s_setprio(0);
        }
    }

    // ---------------- cross-wave reduction through retired KV LDS ----------
    __syncthreads();
    float* Lf = (float*)(&KV[0][0][0]);       // 9216 floats available

    // l: reduce over kq in-wave, write per-wave partials Lf[(half*4+w)*32 + ql]
#pragma unroll
    for (int h2 = 0; h2 < 2; ++h2)
#pragma unroll
        for (int c = 0; c < 2; ++c) {
            float v = ls[h2][c];
            v += __shfl_xor(v, 16);
            v += __shfl_xor(v, 32);
            if (kq == 0) Lf[(h2 * 4 + w) * 32 + c * 16 + lm] = v;
        }
    __syncthreads();

    // each thread computes linv for the q-rows it will store (rq, per half)
    const int rq = t >> 2;                    // 0..63 (row within half)
    const int dq = (t & 3) * 8;               // d offset within 32-chunk
    const int qgr = rq >> 5, qlr = rq & 31;
    float li[2];
#pragma unroll
    for (int h2 = 0; h2 < 2; ++h2) {
        float l = Lf[(h2 * 4 + qgr * 2) * 32 + qlr] + Lf[(h2 * 4 + qgr * 2 + 1) * 32 + qlr];
#if __has_builtin(__builtin_amdgcn_rcpf)
        li[h2] = __builtin_amdgcn_rcpf(l);
#else
        li[h2] = 1.0f / l;
#endif
    }
    __syncthreads();                          // l reads done before overwrite

    const int b = bh >> 4, h = bh & 15;
    // O: two passes of 32 d-columns; 256 partial rows (2 halves x 4 waves x 32)
    // x 36-float stride = 9216 floats exactly.
#pragma unroll
    for (int p = 0; p < 2; ++p) {
#pragma unroll
        for (int h2 = 0; h2 < 2; ++h2)
#pragma unroll
            for (int c = 0; c < 2; ++c)
#pragma unroll
                for (int djh = 0; djh < 2; ++djh) {
                    const int dj = 2 * p + djh;
#pragma unroll
                    for (int r = 0; r < 4; ++r)
                        Lf[((h2 * 4 + w) * 32 + c * 16 + kq * 4 + r) * 36 + djh * 16 + lm] = o[h2][c][dj][r];
                }
        __syncthreads();
#pragma unroll
        for (int h2 = 0; h2 < 2; ++h2) {
            const int rowA = ((h2 * 4 + qgr * 2) * 32 + qlr) * 36;
            const int rowB = ((h2 * 4 + qgr * 2 + 1) * 32 + qlr) * 36;
            f32x4 a0 = *(const f32x4*)(Lf + rowA + dq) + *(const f32x4*)(Lf + rowB + dq);
            f32x4 a1 = *(const f32x4*)(Lf + rowA + dq + 4) + *(const f32x4*)(Lf + rowB + dq + 4);
            uint4 outv;
            outv.x = pack_bf2(a0[0] * li[h2], a0[1] * li[h2]);
            outv.y = pack_bf2(a0[2] * li[h2], a0[3] * li[h2]);
            outv.z = pack_bf2(a1[0] * li[h2], a1[1] * li[h2]);
            outv.w = pack_bf2(a1[2] * li[h2], a1[3] * li[h2]);
            *(uint4*)(Og + (((size_t)(b * SEQ + qb * 128 + h2 * 64 + rq)) * NHEAD + h) * DKD + p * 32 + dq) = outv;
        }
        __syncthreads();
    }
}

// ---------------------------------------------------------------- launcher
extern "C" void kernel_launch(void* const* d_in, const int* in_sizes, int n_in,
                              void* d_out, int out_size, void* d_ws, size_t ws_size,
                              hipStream_t stream) {
    const float* x  = (const float*)d_in[0];
    const float* Wq = (const float*)d_in[1];
    const float* Wk = (const float*)d_in[2];
    const float* Wv = (const float*)d_in[3];
    const float* Wo = (const float*)d_in[4];
    const float* bo = (const float*)d_in[5];
    float* out = (float*)d_out;

    unsigned short* ws = (unsigned short*)d_ws;
    unsigned short* Xb   = ws;                       // [4096][1024]
    unsigned short* Wqkv = ws + 4194304;             // [3072][1024] (Wq|Wk|Wv)
    unsigned short* Wob  = ws + 7340032;             // [1024][1024]
    unsigned short* QKV  = ws + 8388608;             // Q,K:[b,h,s,d]; V:[b,h,d,s]
    unsigned short* Ob   = ws + 20971520;            // [4096][1024] = [b,s,h,d]

    cast_all<<<8192, 256, 0, stream>>>(x, Wq, Wk, Wv, Wo, Xb, Wqkv, Wob);
    gemm_bt<0, 128><<<dim3(32, 24), 256, 0, stream>>>(Xb, Wqkv, QKV, nullptr, nullptr);
    attn_kernel<<<512, 256, 0, stream>>>(QKV, QKV + 4194304, QKV + 8388608, Ob);
    gemm_bt<1, 64><<<dim3(32, 16), 256, 0, stream>>>(Ob, Wob, nullptr, out, bo);
}

// Round 12
// 176.454 us; speedup vs baseline: 2.0589x; 1.0189x over previous
//
#include <hip/hip_runtime.h>

// ---------------------------------------------------------------------------
// MultiheadSelfAttention: B=2, S=2048, D=1024, H=16, DK=64
// cast->bf16 ; fused QKV GEMM (BK=32 double-buffered pipeline + XCD-aware
// block remap) ; flash attention (R7-proven: 128-row Q tile, 2x2 q/key wave
// split, two q-halves sharing K/V frags, KVBLK=64, no-max exp2 softmax, PV
// via full-rate K=32 MFMA, lgkm-only barrier) ; output projection (dedicated
// BK=64 double-buffered kernel: 16 barrier-intervals x 16 MFMA + XCD remap).
// Session envelope (measured): cooperative lockstep staging + ~100 live VGPR
// + 2 blocks/CU + 2x q-ILP is the attn optimum. Proven regressions outside:
//  R1 free-run waves (FETCH x6.6), R3 K->reg (spill), R8 KVBLK=128 (spill),
//  R9 counted-vmcnt triple-buffer (neutral), R10 8-wave block (64-VGPR cap).
// ---------------------------------------------------------------------------

typedef __attribute__((ext_vector_type(8))) short bf16x8;   // 8 bf16
typedef __attribute__((ext_vector_type(4))) short bf16x4;   // 4 bf16
typedef __attribute__((ext_vector_type(4))) float f32x4;
typedef __attribute__((ext_vector_type(2))) unsigned int u32x2;
typedef __attribute__((ext_vector_type(4))) unsigned int u32x4;

#define GK 1024
#define SEQ 2048
#define NHEAD 16
#define DKD 64
#define PADW 72      // padded LDS row stride (elems) for attn/epilogue tiles

#define MFMA32(a, b, c) __builtin_amdgcn_mfma_f32_16x16x32_bf16((a), (b), (c), 0, 0, 0)

#if __has_builtin(__builtin_amdgcn_exp2f)
#define EXP2(x) __builtin_amdgcn_exp2f(x)
#else
#define EXP2(x) exp2f(x)
#endif

// Q scale: (1/sqrt(64)) * log2(e), folded into the Q projection epilogue
#define QSCALE 0.18033688011f

static __device__ __forceinline__ unsigned short f2bf(float f) {
    unsigned int u = __float_as_uint(f);
    u += 0x7fffu + ((u >> 16) & 1u);     // RNE
    return (unsigned short)(u >> 16);
}

// pack two f32 -> two bf16 in one dword (a -> low half). round-half-up + v_perm.
static __device__ __forceinline__ unsigned int pack_bf2(float a, float b) {
    unsigned int ua = __float_as_uint(a) + 0x8000u;
    unsigned int ub = __float_as_uint(b) + 0x8000u;
    return __builtin_amdgcn_perm(ub, ua, 0x07060302u);  // [b.hi16, a.hi16]
}

// XCD-aware block remap (T1): linear id -> contiguous per-XCD chunk.
// Requires nwg % 8 == 0 and gridDim.x == 32 (both true here). Bijective.
static __device__ __forceinline__ int xcd_remap(int nwg) {
    const int lid = blockIdx.x + 32 * blockIdx.y;
    return (lid & 7) * (nwg >> 3) + (lid >> 3);
}

// ---------------------------------------------------------------- fused casts
__global__ __launch_bounds__(256) void cast_all(const float* __restrict__ x,
                                                const float* __restrict__ wq,
                                                const float* __restrict__ wk,
                                                const float* __restrict__ wv,
                                                const float* __restrict__ wo,
                                                unsigned short* __restrict__ Xb,
                                                unsigned short* __restrict__ Wqkv,
                                                unsigned short* __restrict__ Wob) {
    const int bid = blockIdx.x;
    const float* src; unsigned short* dst; int off;
    if (bid < 4096)      { src = x;  dst = Xb;             off = bid; }
    else if (bid < 5120) { src = wq; dst = Wqkv;           off = bid - 4096; }
    else if (bid < 6144) { src = wk; dst = Wqkv + 1048576; off = bid - 5120; }
    else if (bid < 7168) { src = wv; dst = Wqkv + 2097152; off = bid - 6144; }
    else                 { src = wo; dst = Wob;            off = bid - 7168; }
    const int i = off * 1024 + threadIdx.x * 4;
    float4 v = *(const float4*)(src + i);
    u32x2 p; p.x = pack_bf2(v.x, v.y); p.y = pack_bf2(v.z, v.w);
    *(u32x2*)(dst + i) = p;
}

// ---------------------------------------------------------------- GEMM C = A * B^T
// R7-PROVEN BK=32 DOUBLE-BUFFERED K-loop (32 steps, ONE barrier each):
//   barrier -> issue global_load_lds for tile k+1 into the other buffer
//           -> ds_read frags + 16 MFMA on tile k.
// The barrier's vmcnt(0) drain waits for loads issued one full compute-phase
// earlier (latency hidden). Rows are 4 x 16B chunks, XOR-swizzled: LDS chunk
// c' of row r holds global chunk c'^(r&3) (per-lane GLOBAL address permuted;
// LDS dest stays uniform+lane*16B as global_load_lds requires). MODE 0: QKV
// epilogue via per-wave LDS scratch UNIONED with the loop buffers.
// + XCD-aware block remap (each XCD covers a contiguous by-range -> B-panels
// become XCD-L2-resident instead of replicated across 8 L2s).
template <int MODE, int BN>
__global__ __launch_bounds__(256) void gemm_bt(const unsigned short* __restrict__ A,
                                               const unsigned short* __restrict__ Bw,
                                               unsigned short* __restrict__ outb,
                                               float* __restrict__ outf,
                                               const float* __restrict__ bias) {
    constexpr int NJ = BN / 32;
    constexpr int TILE = (128 + BN) * 32;            // elems per buffer (A then B)
    constexpr int LOOP_BYTES = 2 * TILE * 2;         // double-buffered
    constexpr int EPI_BYTES  = 4 * 64 * PADW * 2;
    constexpr int SMEM_BYTES = (MODE == 0)
        ? (LOOP_BYTES > EPI_BYTES ? LOOP_BYTES : EPI_BYTES)
        : LOOP_BYTES;
    __shared__ __align__(16) unsigned char SMEM[SMEM_BYTES];
    unsigned short* Buf0 = (unsigned short*)SMEM;    // A[128][32] + B[BN][32], swizzled
    unsigned short* Buf1 = Buf0 + TILE;

    const int t    = threadIdx.x;
    const int lane = t & 63;
    const int w    = t >> 6;
    const int wm   = (w >> 1) * 64;
    const int wn   = (w & 1) * (BN / 2);
    const int sid  = xcd_remap(32 * gridDim.y);
    const int bm0  = (sid & 31) * 128;
    const int bn0  = (sid >> 5) * BN;
    const int lm   = lane & 15;
    const int lq   = lane >> 4;
    const int swz  = (lq ^ (lm & 3)) * 8;   // un-swizzled chunk offset (elems)

    const unsigned short* Ab = A + (size_t)bm0 * GK;
    const unsigned short* Bb = Bw + (size_t)bn0 * GK;

    f32x4 acc[4][NJ];
    const f32x4 Z4 = {0.f, 0.f, 0.f, 0.f};
#pragma unroll
    for (int i = 0; i < 4; i++)
#pragma unroll
        for (int j = 0; j < NJ; j++) acc[i][j] = Z4;

    const int q_uni = (t & ~63);

    // stage one BK=32 tile (A + B) into buffer Bp, async via global_load_lds
    auto STAGE = [&](unsigned short* Bp, int k0) {
        // A: 128 rows x 4 chunks = 512 chunks, 2 per thread
#pragma unroll
        for (int i = 0; i < 2; ++i) {
            int q  = i * 256 + t;
            int r  = q >> 2;
            int gc = (q & 3) ^ (r & 3);          // global col chunk (swizzle)
            int q0 = i * 256 + q_uni;
            __builtin_amdgcn_global_load_lds(
                (const __attribute__((address_space(1))) void*)(Ab + (size_t)r * GK + k0 + gc * 8),
                (__attribute__((address_space(3))) void*)(Bp + (size_t)q0 * 8),
                16, 0, 0);
        }
        // B: BN rows x 4 chunks, BN/64 per thread
#pragma unroll
        for (int i = 0; i < BN / 64; ++i) {
            int q  = i * 256 + t;
            int r  = q >> 2;
            int gc = (q & 3) ^ (r & 3);
            int q0 = i * 256 + q_uni;
            __builtin_amdgcn_global_load_lds(
                (const __attribute__((address_space(1))) void*)(Bb + (size_t)r * GK + k0 + gc * 8),
                (__attribute__((address_space(3))) void*)(Bp + 128 * 32 + (size_t)q0 * 8),
                16, 0, 0);
        }
    };

    STAGE(Buf0, 0);                          // prologue: tile 0 in flight
    for (int ks = 0; ks < GK / 32; ++ks) {
        __syncthreads();                     // tile ks landed; prev reads retired
        unsigned short* Cur = (ks & 1) ? Buf1 : Buf0;
        unsigned short* Nxt = (ks & 1) ? Buf0 : Buf1;
        if (ks + 1 < GK / 32) STAGE(Nxt, (ks + 1) * 32);  // async, hides under compute

        bf16x8 af[4], bf[NJ];
#pragma unroll
        for (int i = 0; i < 4; i++)
            af[i] = *(const bf16x8*)(Cur + (wm + i * 16 + lm) * 32 + swz);
#pragma unroll
        for (int j = 0; j < NJ; j++)
            bf[j] = *(const bf16x8*)(Cur + 128 * 32 + (wn + j * 16 + lm) * 32 + swz);
#pragma unroll
        for (int i = 0; i < 4; i++)
#pragma unroll
            for (int j = 0; j < NJ; j++)
                acc[i][j] = MFMA32(af[i], bf[j], acc[i][j]);
    }

    if (MODE == 0) {
        __syncthreads();                         // all K-loop LDS reads retired
        unsigned short* E  = (unsigned short*)SMEM;   // union with loop buffers
        unsigned short* Ew = E + w * (64 * PADW);
        const int nbase = bn0 + wn;
        const int which = nbase >> 10;            // 0=Q 1=K 2=V
        const int hh    = (nbase & 1023) >> 6;
        const int lq4   = lq * 4;
        if (which != 2) {
            const float sc = (which == 0) ? QSCALE : 1.0f;
#pragma unroll
            for (int i = 0; i < 4; i++)
#pragma unroll
                for (int j = 0; j < 4; j++)
#pragma unroll
                    for (int r = 0; r < 4; r++)
                        Ew[(i * 16 + lq4 + r) * PADW + j * 16 + lm] =
                            f2bf(acc[i][j][r] * sc);
            unsigned short* dst = outb + (size_t)which * 4194304;
#pragma unroll
            for (int rep = 0; rep < 8; ++rep) {
                const int mm = rep * 8 + (lane >> 3);
                const int d0 = (lane & 7) * 8;
                uint4 v = *(const uint4*)(Ew + mm * PADW + d0);
                const int m_g = bm0 + wm + mm;
                const int b = m_g >> 11, s = m_g & 2047;
                *(uint4*)(dst + (((size_t)(b * NHEAD + hh)) * SEQ + s) * DKD + d0) = v;
            }
        } else {
#pragma unroll
            for (int i = 0; i < 4; i++)
#pragma unroll
                for (int j = 0; j < 4; j++) {
                    u32x2 pk;
                    pk.x = pack_bf2(acc[i][j][0], acc[i][j][1]);
                    pk.y = pack_bf2(acc[i][j][2], acc[i][j][3]);
                    *(u32x2*)(Ew + (j * 16 + lm) * PADW + i * 16 + lq4) = pk;
                }
            unsigned short* dst = outb + (size_t)2 * 4194304;
#pragma unroll
            for (int rep = 0; rep < 8; ++rep) {
                const int nn = rep * 8 + (lane >> 3);
                const int mc = (lane & 7) * 8;
                uint4 v = *(const uint4*)(Ew + nn * PADW + mc);
                const int m_g = bm0 + wm + mc;
                const int b = m_g >> 11, s0 = m_g & 2047;
                *(uint4*)(dst + (((size_t)(b * NHEAD + hh)) * DKD + nn) * SEQ + s0) = v;
            }
        }
    } else {
#pragma unroll
        for (int i = 0; i < 4; i++) {
            const int mbase = bm0 + wm + i * 16 + lq * 4;
#pragma unroll
            for (int j = 0; j < NJ; j++) {
                const int n = bn0 + wn + j * 16 + lm;
#pragma unroll
                for (int r = 0; r < 4; r++)
                    outf[(size_t)(mbase + r) * 1024 + n] = acc[i][j][r] + bias[n];
            }
        }
    }
}

// ---------------------------------------------------------------- output GEMM
// Dedicated BK=64 DOUBLE-BUFFERED kernel for the output projection (BN=64):
// 16 barrier-intervals x 16 MFMA/wave (vs BK=32's 32 x 8 — twice the MFMA
// density per staging/barrier interval for this narrow-N GEMM). Staging and
// fragment-read swizzle are the R0-verified 8-chunk XOR pattern: LDS chunk c'
// of row r holds global chunk c'^(r&7); reads un-swizzle with
// ((kk*4+lq)^(lm&7))*8. Pipeline structure is R7's: barrier -> STAGE(k+1) ->
// compute(k). LDS 2 x 24,576 B = 49,152 -> 3 blocks/CU capacity, grid 512 =
// 2/CU resident. + XCD-aware block remap.
__global__ __launch_bounds__(256) void gemm_out(const unsigned short* __restrict__ A,
                                                const unsigned short* __restrict__ Bw,
                                                float* __restrict__ outf,
                                                const float* __restrict__ bias) {
    constexpr int BN = 64;
    constexpr int TILE = (128 + BN) * 64;            // elems per buffer (A then B)
    __shared__ __align__(16) unsigned short Buf[2 * TILE];   // 49,152 B

    const int t    = threadIdx.x;
    const int lane = t & 63;
    const int w    = t >> 6;
    const int wm   = (w >> 1) * 64;
    const int wn   = (w & 1) * 32;
    const int sid  = xcd_remap(32 * gridDim.y);
    const int bm0  = (sid & 31) * 128;
    const int bn0  = (sid >> 5) * BN;
    const int lm   = lane & 15;
    const int lq   = lane >> 4;
    const int swzb = lm & 7;                 // row&7 for all frag rows

    const unsigned short* Ab = A + (size_t)bm0 * GK;
    const unsigned short* Bb = Bw + (size_t)bn0 * GK;

    f32x4 acc[4][2];
    const f32x4 Z4 = {0.f, 0.f, 0.f, 0.f};
#pragma unroll
    for (int i = 0; i < 4; i++)
#pragma unroll
        for (int j = 0; j < 2; j++) acc[i][j] = Z4;

    const int q_uni = (t & ~63);

    // stage one BK=64 tile (A[128][64] + B[64][64]) into buffer Bp
    auto STAGE = [&](unsigned short* Bp, int k0) {
        // A: 128 rows x 8 chunks = 1024 chunks, 4 per thread
#pragma unroll
        for (int i = 0; i < 4; ++i) {
            int q  = i * 256 + t;
            int r  = q >> 3;
            int gc = (q & 7) ^ (r & 7);          // global col chunk (swizzle)
            int q0 = i * 256 + q_uni;
            __builtin_amdgcn_global_load_lds(
                (const __attribute__((address_space(1))) void*)(Ab + (size_t)r * GK + k0 + gc * 8),
                (__attribute__((address_space(3))) void*)(Bp + (size_t)q0 * 8),
                16, 0, 0);
        }
        // B: 64 rows x 8 chunks = 512 chunks, 2 per thread
#pragma unroll
        for (int i = 0; i < 2; ++i) {
            int q  = i * 256 + t;
            int r  = q >> 3;
            int gc = (q & 7) ^ (r & 7);
            int q0 = i * 256 + q_uni;
            __builtin_amdgcn_global_load_lds(
                (const __attribute__((address_space(1))) void*)(Bb + (size_t)r * GK + k0 + gc * 8),
                (__attribute__((address_space(3))) void*)(Bp + 128 * 64 + (size_t)q0 * 8),
                16, 0, 0);
        }
    };

    STAGE(Buf, 0);                           // prologue: tile 0 in flight
    for (int ks = 0; ks < GK / 64; ++ks) {
        __syncthreads();                     // tile ks landed; prev reads retired
        unsigned short* Cur = Buf + (ks & 1) * TILE;
        unsigned short* Nxt = Buf + ((ks & 1) ^ 1) * TILE;
        if (ks + 1 < GK / 64) STAGE(Nxt, (ks + 1) * 64);  // async, hides under compute

#pragma unroll
        for (int kk = 0; kk < 2; ++kk) {
            const int swz = ((kk * 4 + lq) ^ swzb) * 8;   // un-swizzled col elems
            bf16x8 af[4], bf[2];
#pragma unroll
            for (int i = 0; i < 4; i++)
                af[i] = *(const bf16x8*)(Cur + (wm + i * 16 + lm) * 64 + swz);
#pragma unroll
            for (int j = 0; j < 2; j++)
                bf[j] = *(const bf16x8*)(Cur + 128 * 64 + (wn + j * 16 + lm) * 64 + swz);
#pragma unroll
            for (int i = 0; i < 4; i++)
#pragma unroll
                for (int j = 0; j < 2; j++)
                    acc[i][j] = MFMA32(af[i], bf[j], acc[i][j]);
        }
    }

    // epilogue: fp32 + bias, scalar dword stores (64B-contiguous per 16 lanes)
#pragma unroll
    for (int i = 0; i < 4; i++) {
        const int mbase = bm0 + wm + i * 16 + lq * 4;
#pragma unroll
        for (int j = 0; j < 2; j++) {
            const int n = bn0 + wn + j * 16 + lm;
#pragma unroll
            for (int r = 0; r < 4; r++)
                outf[(size_t)(mbase + r) * 1024 + n] = acc[i][j][r] + bias[n];
        }
    }
}

// ---------------------------------------------------------------- flash attention
// R7-PROVEN VERSION (49.1 us, VGPR 100, no spill). 128-ROW Q TILE, 2x2 SPLIT:
// block covers 128 q rows as TWO 64-row halves; wave w = (qg = w>>1, kg = w&1)
// owns rows half*64 + qg*32..+31 x keys kg*32..+31 of each 64-key tile. Both
// halves processed per K-tile iteration SHARING the same ak/bv LDS fragments
// and the same cooperative staging -> 2x work per staged byte. PV at full K=32
// depth (k-permutation f(kq*8+kc*4+r) = kc*16+kq*4+r applied identically to P
// pack order and V fragment reads -> exact contraction). K-loop barrier is
// lgkm-only (LDS ordering suffices; global prefetch stays in flight).
// Grid 512 = 8 XCD x 4 heads x 16 q-super-blocks, 2 blocks/CU.
__global__ __launch_bounds__(256, 2) void attn_kernel(const unsigned short* __restrict__ Qg,
                                                      const unsigned short* __restrict__ Kg,
                                                      const unsigned short* __restrict__ Vtg,
                                                      unsigned short* __restrict__ Og) {
    __shared__ __align__(16) unsigned short KV[2][2][64 * PADW];  // 36,864 B

    const int id  = blockIdx.x;
    const int xcd = id & 7;
    const int j8  = id >> 3;                 // 0..63
    const int bh  = xcd * 4 + (j8 & 3);      // 4 heads per XCD
    const int qb  = j8 >> 2;                 // 0..15 (128-row q super-blocks)
    const unsigned short* Qp  = Qg  + ((size_t)bh * SEQ + qb * 128) * DKD;
    const unsigned short* Kp  = Kg  + (size_t)bh * SEQ * DKD;
    const unsigned short* Vtp = Vtg + (size_t)bh * DKD * SEQ;

    const int t    = threadIdx.x;
    const int lane = t & 63;
    const int w    = t >> 6;
    const int qg   = w >> 1;       // q-group (32 rows within each 64-row half)
    const int kg   = w & 1;        // key-group (32 keys of each 64-key tile)
    const int lm   = lane & 15;
    const int kq   = lane >> 4;

    const f32x4 Z4 = {0.f, 0.f, 0.f, 0.f};

    // Q B-frags: two 64-row halves, this wave's 32 rows of each
    bf16x8 aq[2][2][2];            // [half][c][kk]
#pragma unroll
    for (int h2 = 0; h2 < 2; ++h2)
#pragma unroll
        for (int c = 0; c < 2; ++c)
#pragma unroll
            for (int kk = 0; kk < 2; ++kk)
                aq[h2][c][kk] = *(const bf16x8*)(Qp + (size_t)(h2 * 64 + qg * 32 + c * 16 + lm) * DKD + kk * 32 + kq * 8);

    f32x4 o[2][2][4];              // [half][q-chunk][d-chunk], partial over 32 keys
    float ls[2][2];                // [half][q-chunk] in-lane l partial
#pragma unroll
    for (int h2 = 0; h2 < 2; ++h2)
#pragma unroll
        for (int c = 0; c < 2; ++c) {
            ls[h2][c] = 0.f;
#pragma unroll
            for (int dj = 0; dj < 4; ++dj) o[h2][c][dj] = Z4;
        }

    // staging: K tile [64 key][64 d], V tile [64 d][64 key]; 2 uint4/thread each
    const int sr = t >> 2, sc = (t & 3) * 16;
    uint4 kreg0, kreg1, vreg0, vreg1;
    {   // tile 0 -> buf 0
        const unsigned short* kp = Kp + (size_t)sr * DKD + sc;
        const unsigned short* vp = Vtp + (size_t)sr * SEQ + sc;
        uint4 a0 = *(const uint4*)(kp), a1 = *(const uint4*)(kp + 8);
        uint4 b0 = *(const uint4*)(vp), b1 = *(const uint4*)(vp + 8);
        uint4* dk = (uint4*)(&KV[0][0][sr * PADW + sc]); dk[0] = a0; dk[1] = a1;
        uint4* dv = (uint4*)(&KV[0][1][sr * PADW + sc]); dv[0] = b0; dv[1] = b1;
    }
    {   // prefetch tile 1
        const unsigned short* kp = Kp + (size_t)(64 + sr) * DKD + sc;
        kreg0 = *(const uint4*)(kp); kreg1 = *(const uint4*)(kp + 8);
        const unsigned short* vp = Vtp + (size_t)sr * SEQ + 64 + sc;
        vreg0 = *(const uint4*)(vp); vreg1 = *(const uint4*)(vp + 8);
    }

    for (int kt = 0; kt < 32; ++kt) {
        // lgkm-only barrier: LDS ordering only; global prefetch stays in flight
        asm volatile("s_waitcnt lgkmcnt(0)\n\ts_barrier" ::: "memory");
        const unsigned short* Kc = &KV[kt & 1][0][0];
        const unsigned short* Vc = &KV[kt & 1][1][0];

        // K A-frags for this wave's 32 keys (issued first; in-order lgkm)
        bf16x8 ak[2][2];
#pragma unroll
        for (int kc = 0; kc < 2; ++kc)
#pragma unroll
            for (int kk = 0; kk < 2; ++kk)
                ak[kc][kk] = *(const bf16x8*)(Kc + (kg * 32 + kc * 16 + lm) * PADW + kk * 32 + kq * 8);

        // write prefetched tile kt+1 -> other buf (its readers retired pre-barrier)
        if (kt + 1 < 32) {
            uint4* dk = (uint4*)(&KV[(kt + 1) & 1][0][sr * PADW + sc]);
            dk[0] = kreg0; dk[1] = kreg1;
            uint4* dv = (uint4*)(&KV[(kt + 1) & 1][1][sr * PADW + sc]);
            dv[0] = vreg0; dv[1] = vreg1;
        }
        if (kt + 2 < 32) {
            const unsigned short* kp = Kp + (size_t)((kt + 2) * 64 + sr) * DKD + sc;
            kreg0 = *(const uint4*)(kp); kreg1 = *(const uint4*)(kp + 8);
            const unsigned short* vp = Vtp + (size_t)sr * SEQ + (kt + 2) * 64 + sc;
            vreg0 = *(const uint4*)(vp); vreg1 = *(const uint4*)(vp + 8);
        }

        // V B-frags under permutation f (shared by both q-halves)
        bf16x8 bv[4];
#pragma unroll
        for (int dj = 0; dj < 4; ++dj) {
            const unsigned short* vr = Vc + (dj * 16 + lm) * PADW + kg * 32;
            u32x2 lo = __builtin_bit_cast(u32x2, *(const bf16x4*)(vr + kq * 4));
            u32x2 hi = __builtin_bit_cast(u32x2, *(const bf16x4*)(vr + 16 + kq * 4));
            u32x4 uu; uu.x = lo.x; uu.y = lo.y; uu.z = hi.x; uu.w = hi.y;
            bv[dj] = __builtin_bit_cast(bf16x8, uu);
        }

        // two independent q-halves share ak/bv: 2x work per staged byte
#pragma unroll
        for (int h2 = 0; h2 < 2; ++h2) {
            // S^T[32 keys][32 q]: s[kc][c], lane holds key kc*16+kq*4+r, q c*16+lm
            f32x4 s[2][2];
            __builtin_amdgcn_s_setprio(1);
#pragma unroll
            for (int kc = 0; kc < 2; ++kc)
#pragma unroll
                for (int c = 0; c < 2; ++c) {
                    s[kc][c] = MFMA32(ak[kc][0], aq[h2][c][0], Z4);
                    s[kc][c] = MFMA32(ak[kc][1], aq[h2][c][1], s[kc][c]);
                }
            __builtin_amdgcn_s_setprio(0);

            // p = exp2(s); accumulate in-lane l over both key sub-chunks
#pragma unroll
            for (int c = 0; c < 2; ++c) {
#pragma unroll
                for (int kc = 0; kc < 2; ++kc)
#pragma unroll
                    for (int r = 0; r < 4; ++r) s[kc][c][r] = EXP2(s[kc][c][r]);
                ls[h2][c] += ((s[0][c][0] + s[0][c][1]) + (s[0][c][2] + s[0][c][3]))
                           + ((s[1][c][0] + s[1][c][1]) + (s[1][c][2] + s[1][c][3]));
            }

            // pack P under f: element j=kc*4+r = P[q=lm][key kc*16+kq*4+r]
            bf16x8 pa[2];
#pragma unroll
            for (int c = 0; c < 2; ++c) {
                u32x4 uu;
                uu.x = pack_bf2(s[0][c][0], s[0][c][1]);
                uu.y = pack_bf2(s[0][c][2], s[0][c][3]);
                uu.z = pack_bf2(s[1][c][0], s[1][c][1]);
                uu.w = pack_bf2(s[1][c][2], s[1][c][3]);
                pa[c] = __builtin_bit_cast(bf16x8, uu);
            }

            // O += P V over this wave's 32 keys — full K=32 MFMA
            __builtin_amdgcn_s_setprio(1);
#pragma unroll
            for (int dj = 0; dj < 4; ++dj)
#pragma unroll
                for (int c = 0; c < 2; ++c)
                    o[h2][c][dj] = MFMA32(pa[c], bv[dj], o[h2][c][dj]);
            __builtin_amdgcn_s_setprio(0);
        }
    }

    // ---------------- cross-wave reduction through retired KV LDS ----------
    __syncthreads();
    float* Lf = (float*)(&KV[0][0][0]);       // 9216 floats available

    // l: reduce over kq in-wave, write per-wave partials Lf[(half*4+w)*32 + ql]
#pragma unroll
    for (int h2 = 0; h2 < 2; ++h2)
#pragma unroll
        for (int c = 0; c < 2; ++c) {
            float v = ls[h2][c];
            v += __shfl_xor(v, 16);
            v += __shfl_xor(v, 32);
            if (kq == 0) Lf[(h2 * 4 + w) * 32 + c * 16 + lm] = v;
        }
    __syncthreads();

    // each thread computes linv for the q-rows it will store (rq, per half)
    const int rq = t >> 2;                    // 0..63 (row within half)
    const int dq = (t & 3) * 8;               // d offset within 32-chunk
    const int qgr = rq >> 5, qlr = rq & 31;
    float li[2];
#pragma unroll
    for (int h2 = 0; h2 < 2; ++h2) {
        float l = Lf[(h2 * 4 + qgr * 2) * 32 + qlr] + Lf[(h2 * 4 + qgr * 2 + 1) * 32 + qlr];
#if __has_builtin(__builtin_amdgcn_rcpf)
        li[h2] = __builtin_amdgcn_rcpf(l);
#else
        li[h2] = 1.0f / l;
#endif
    }
    __syncthreads();                          // l reads done before overwrite

    const int b = bh >> 4, h = bh & 15;
    // O: two passes of 32 d-columns; 256 partial rows (2 halves x 4 waves x 32)
    // x 36-float stride = 9216 floats exactly.
#pragma unroll
    for (int p = 0; p < 2; ++p) {
#pragma unroll
        for (int h2 = 0; h2 < 2; ++h2)
#pragma unroll
            for (int c = 0; c < 2; ++c)
#pragma unroll
                for (int djh = 0; djh < 2; ++djh) {
                    const int dj = 2 * p + djh;
#pragma unroll
                    for (int r = 0; r < 4; ++r)
                        Lf[((h2 * 4 + w) * 32 + c * 16 + kq * 4 + r) * 36 + djh * 16 + lm] = o[h2][c][dj][r];
                }
        __syncthreads();
#pragma unroll
        for (int h2 = 0; h2 < 2; ++h2) {
            const int rowA = ((h2 * 4 + qgr * 2) * 32 + qlr) * 36;
            const int rowB = ((h2 * 4 + qgr * 2 + 1) * 32 + qlr) * 36;
            f32x4 a0 = *(const f32x4*)(Lf + rowA + dq) + *(const f32x4*)(Lf + rowB + dq);
            f32x4 a1 = *(const f32x4*)(Lf + rowA + dq + 4) + *(const f32x4*)(Lf + rowB + dq + 4);
            uint4 outv;
            outv.x = pack_bf2(a0[0] * li[h2], a0[1] * li[h2]);
            outv.y = pack_bf2(a0[2] * li[h2], a0[3] * li[h2]);
            outv.z = pack_bf2(a1[0] * li[h2], a1[1] * li[h2]);
            outv.w = pack_bf2(a1[2] * li[h2], a1[3] * li[h2]);
            *(uint4*)(Og + (((size_t)(b * SEQ + qb * 128 + h2 * 64 + rq)) * NHEAD + h) * DKD + p * 32 + dq) = outv;
        }
        __syncthreads();
    }
}

// ---------------------------------------------------------------- launcher
extern "C" void kernel_launch(void* const* d_in, const int* in_sizes, int n_in,
                              void* d_out, int out_size, void* d_ws, size_t ws_size,
                              hipStream_t stream) {
    const float* x  = (const float*)d_in[0];
    const float* Wq = (const float*)d_in[1];
    const float* Wk = (const float*)d_in[2];
    const float* Wv = (const float*)d_in[3];
    const float* Wo = (const float*)d_in[4];
    const float* bo = (const float*)d_in[5];
    float* out = (float*)d_out;

    unsigned short* ws = (unsigned short*)d_ws;
    unsigned short* Xb   = ws;                       // [4096][1024]
    unsigned short* Wqkv = ws + 4194304;             // [3072][1024] (Wq|Wk|Wv)
    unsigned short* Wob  = ws + 7340032;             // [1024][1024]
    unsigned short* QKV  = ws + 8388608;             // Q,K:[b,h,s,d]; V:[b,h,d,s]
    unsigned short* Ob   = ws + 20971520;            // [4096][1024] = [b,s,h,d]

    cast_all<<<8192, 256, 0, stream>>>(x, Wq, Wk, Wv, Wo, Xb, Wqkv, Wob);
    gemm_bt<0, 128><<<dim3(32, 24), 256, 0, stream>>>(Xb, Wqkv, QKV, nullptr, nullptr);
    attn_kernel<<<512, 256, 0, stream>>>(QKV, QKV + 4194304, QKV + 8388608, Ob);
    gemm_out<<<dim3(32, 16), 256, 0, stream>>>(Ob, Wob, out, bo);
}

// Round 13
// 172.453 us; speedup vs baseline: 2.1066x; 1.0232x over previous
//
#include <hip/hip_runtime.h>

// ---------------------------------------------------------------------------
// MultiheadSelfAttention: B=2, S=2048, D=1024, H=16, DK=64
// cast->bf16 ; fused QKV GEMM (BK=32 double-buffered pipeline + XCD remap) ;
// flash attention (R7-proven structure: 128-row Q tile, 2x2 q/key wave split,
// two q-halves sharing K/V frags, KVBLK=64, no-max exp2 softmax, PV via
// full-rate K=32 MFMA, lgkm-only barrier; NEW: P->bf16 via v_cvt_pk_bf16_f32
// (1 instr vs 3) and l-row-sum via ones-MFMA on the matrix pipe (replaces 28
// VALU adds/iter + epilogue shfl-reduce)) ; output projection (BK=64 dbuf).
// Session envelope (measured): cooperative lockstep staging + ~100-115 live
// VGPR + 2 blocks/CU + 2x q-ILP is the attn optimum. Proven regressions:
//  R1 free-run waves (FETCH x6.6), R3 K->reg (spill), R8 KVBLK=128 (spill),
//  R9 counted-vmcnt triple-buffer (neutral), R10 8-wave block (64-VGPR cap).
// ---------------------------------------------------------------------------

typedef __attribute__((ext_vector_type(8))) short bf16x8;   // 8 bf16
typedef __attribute__((ext_vector_type(4))) short bf16x4;   // 4 bf16
typedef __attribute__((ext_vector_type(4))) float f32x4;
typedef __attribute__((ext_vector_type(2))) unsigned int u32x2;
typedef __attribute__((ext_vector_type(4))) unsigned int u32x4;

#define GK 1024
#define SEQ 2048
#define NHEAD 16
#define DKD 64
#define PADW 72      // padded LDS row stride (elems) for attn/epilogue tiles

#define MFMA32(a, b, c) __builtin_amdgcn_mfma_f32_16x16x32_bf16((a), (b), (c), 0, 0, 0)

#if __has_builtin(__builtin_amdgcn_exp2f)
#define EXP2(x) __builtin_amdgcn_exp2f(x)
#else
#define EXP2(x) exp2f(x)
#endif

// Q scale: (1/sqrt(64)) * log2(e), folded into the Q projection epilogue
#define QSCALE 0.18033688011f

static __device__ __forceinline__ unsigned short f2bf(float f) {
    unsigned int u = __float_as_uint(f);
    u += 0x7fffu + ((u >> 16) & 1u);     // RNE
    return (unsigned short)(u >> 16);
}

// pack two f32 -> two bf16 in one dword (a -> low half). round-half-up + v_perm.
static __device__ __forceinline__ unsigned int pack_bf2(float a, float b) {
    unsigned int ua = __float_as_uint(a) + 0x8000u;
    unsigned int ub = __float_as_uint(b) + 0x8000u;
    return __builtin_amdgcn_perm(ub, ua, 0x07060302u);  // [b.hi16, a.hi16]
}

// HW packed f32->bf16 convert (RNE): ONE VALU instr vs pack_bf2's three.
// dst low16 = cvt(a), high16 = cvt(b) — same layout as pack_bf2(a,b).
static __device__ __forceinline__ unsigned int cvt_pk_bf16(float a, float b) {
    unsigned int r;
    asm("v_cvt_pk_bf16_f32 %0, %1, %2" : "=v"(r) : "v"(a), "v"(b));
    return r;
}

// XCD-aware block remap (T1): linear id -> contiguous per-XCD chunk.
// Requires nwg % 8 == 0 and gridDim.x == 32 (both true here). Bijective.
static __device__ __forceinline__ int xcd_remap(int nwg) {
    const int lid = blockIdx.x + 32 * blockIdx.y;
    return (lid & 7) * (nwg >> 3) + (lid >> 3);
}

// ---------------------------------------------------------------- fused casts
__global__ __launch_bounds__(256) void cast_all(const float* __restrict__ x,
                                                const float* __restrict__ wq,
                                                const float* __restrict__ wk,
                                                const float* __restrict__ wv,
                                                const float* __restrict__ wo,
                                                unsigned short* __restrict__ Xb,
                                                unsigned short* __restrict__ Wqkv,
                                                unsigned short* __restrict__ Wob) {
    const int bid = blockIdx.x;
    const float* src; unsigned short* dst; int off;
    if (bid < 4096)      { src = x;  dst = Xb;             off = bid; }
    else if (bid < 5120) { src = wq; dst = Wqkv;           off = bid - 4096; }
    else if (bid < 6144) { src = wk; dst = Wqkv + 1048576; off = bid - 5120; }
    else if (bid < 7168) { src = wv; dst = Wqkv + 2097152; off = bid - 6144; }
    else                 { src = wo; dst = Wob;            off = bid - 7168; }
    const int i = off * 1024 + threadIdx.x * 4;
    float4 v = *(const float4*)(src + i);
    u32x2 p; p.x = pack_bf2(v.x, v.y); p.y = pack_bf2(v.z, v.w);
    *(u32x2*)(dst + i) = p;
}

// ---------------------------------------------------------------- GEMM C = A * B^T
// R7-PROVEN BK=32 DOUBLE-BUFFERED K-loop (32 steps, ONE barrier each):
//   barrier -> issue global_load_lds for tile k+1 into the other buffer
//           -> ds_read frags + 16 MFMA on tile k.
// The barrier's vmcnt(0) drain waits for loads issued one full compute-phase
// earlier (latency hidden). Rows are 4 x 16B chunks, XOR-swizzled: LDS chunk
// c' of row r holds global chunk c'^(r&3) (per-lane GLOBAL address permuted;
// LDS dest stays uniform+lane*16B as global_load_lds requires). MODE 0: QKV
// epilogue via per-wave LDS scratch UNIONED with the loop buffers.
// + XCD-aware block remap (B-panels XCD-L2-resident).
template <int MODE, int BN>
__global__ __launch_bounds__(256) void gemm_bt(const unsigned short* __restrict__ A,
                                               const unsigned short* __restrict__ Bw,
                                               unsigned short* __restrict__ outb,
                                               float* __restrict__ outf,
                                               const float* __restrict__ bias) {
    constexpr int NJ = BN / 32;
    constexpr int TILE = (128 + BN) * 32;            // elems per buffer (A then B)
    constexpr int LOOP_BYTES = 2 * TILE * 2;         // double-buffered
    constexpr int EPI_BYTES  = 4 * 64 * PADW * 2;
    constexpr int SMEM_BYTES = (MODE == 0)
        ? (LOOP_BYTES > EPI_BYTES ? LOOP_BYTES : EPI_BYTES)
        : LOOP_BYTES;
    __shared__ __align__(16) unsigned char SMEM[SMEM_BYTES];
    unsigned short* Buf0 = (unsigned short*)SMEM;    // A[128][32] + B[BN][32], swizzled
    unsigned short* Buf1 = Buf0 + TILE;

    const int t    = threadIdx.x;
    const int lane = t & 63;
    const int w    = t >> 6;
    const int wm   = (w >> 1) * 64;
    const int wn   = (w & 1) * (BN / 2);
    const int sid  = xcd_remap(32 * gridDim.y);
    const int bm0  = (sid & 31) * 128;
    const int bn0  = (sid >> 5) * BN;
    const int lm   = lane & 15;
    const int lq   = lane >> 4;
    const int swz  = (lq ^ (lm & 3)) * 8;   // un-swizzled chunk offset (elems)

    const unsigned short* Ab = A + (size_t)bm0 * GK;
    const unsigned short* Bb = Bw + (size_t)bn0 * GK;

    f32x4 acc[4][NJ];
    const f32x4 Z4 = {0.f, 0.f, 0.f, 0.f};
#pragma unroll
    for (int i = 0; i < 4; i++)
#pragma unroll
        for (int j = 0; j < NJ; j++) acc[i][j] = Z4;

    const int q_uni = (t & ~63);

    // stage one BK=32 tile (A + B) into buffer Bp, async via global_load_lds
    auto STAGE = [&](unsigned short* Bp, int k0) {
        // A: 128 rows x 4 chunks = 512 chunks, 2 per thread
#pragma unroll
        for (int i = 0; i < 2; ++i) {
            int q  = i * 256 + t;
            int r  = q >> 2;
            int gc = (q & 3) ^ (r & 3);          // global col chunk (swizzle)
            int q0 = i * 256 + q_uni;
            __builtin_amdgcn_global_load_lds(
                (const __attribute__((address_space(1))) void*)(Ab + (size_t)r * GK + k0 + gc * 8),
                (__attribute__((address_space(3))) void*)(Bp + (size_t)q0 * 8),
                16, 0, 0);
        }
        // B: BN rows x 4 chunks, BN/64 per thread
#pragma unroll
        for (int i = 0; i < BN / 64; ++i) {
            int q  = i * 256 + t;
            int r  = q >> 2;
            int gc = (q & 3) ^ (r & 3);
            int q0 = i * 256 + q_uni;
            __builtin_amdgcn_global_load_lds(
                (const __attribute__((address_space(1))) void*)(Bb + (size_t)r * GK + k0 + gc * 8),
                (__attribute__((address_space(3))) void*)(Bp + 128 * 32 + (size_t)q0 * 8),
                16, 0, 0);
        }
    };

    STAGE(Buf0, 0);                          // prologue: tile 0 in flight
    for (int ks = 0; ks < GK / 32; ++ks) {
        __syncthreads();                     // tile ks landed; prev reads retired
        unsigned short* Cur = (ks & 1) ? Buf1 : Buf0;
        unsigned short* Nxt = (ks & 1) ? Buf0 : Buf1;
        if (ks + 1 < GK / 32) STAGE(Nxt, (ks + 1) * 32);  // async, hides under compute

        bf16x8 af[4], bf[NJ];
#pragma unroll
        for (int i = 0; i < 4; i++)
            af[i] = *(const bf16x8*)(Cur + (wm + i * 16 + lm) * 32 + swz);
#pragma unroll
        for (int j = 0; j < NJ; j++)
            bf[j] = *(const bf16x8*)(Cur + 128 * 32 + (wn + j * 16 + lm) * 32 + swz);
#pragma unroll
        for (int i = 0; i < 4; i++)
#pragma unroll
            for (int j = 0; j < NJ; j++)
                acc[i][j] = MFMA32(af[i], bf[j], acc[i][j]);
    }

    if (MODE == 0) {
        __syncthreads();                         // all K-loop LDS reads retired
        unsigned short* E  = (unsigned short*)SMEM;   // union with loop buffers
        unsigned short* Ew = E + w * (64 * PADW);
        const int nbase = bn0 + wn;
        const int which = nbase >> 10;            // 0=Q 1=K 2=V
        const int hh    = (nbase & 1023) >> 6;
        const int lq4   = lq * 4;
        if (which != 2) {
            const float sc = (which == 0) ? QSCALE : 1.0f;
#pragma unroll
            for (int i = 0; i < 4; i++)
#pragma unroll
                for (int j = 0; j < 4; j++)
#pragma unroll
                    for (int r = 0; r < 4; r++)
                        Ew[(i * 16 + lq4 + r) * PADW + j * 16 + lm] =
                            f2bf(acc[i][j][r] * sc);
            unsigned short* dst = outb + (size_t)which * 4194304;
#pragma unroll
            for (int rep = 0; rep < 8; ++rep) {
                const int mm = rep * 8 + (lane >> 3);
                const int d0 = (lane & 7) * 8;
                uint4 v = *(const uint4*)(Ew + mm * PADW + d0);
                const int m_g = bm0 + wm + mm;
                const int b = m_g >> 11, s = m_g & 2047;
                *(uint4*)(dst + (((size_t)(b * NHEAD + hh)) * SEQ + s) * DKD + d0) = v;
            }
        } else {
#pragma unroll
            for (int i = 0; i < 4; i++)
#pragma unroll
                for (int j = 0; j < 4; j++) {
                    u32x2 pk;
                    pk.x = pack_bf2(acc[i][j][0], acc[i][j][1]);
                    pk.y = pack_bf2(acc[i][j][2], acc[i][j][3]);
                    *(u32x2*)(Ew + (j * 16 + lm) * PADW + i * 16 + lq4) = pk;
                }
            unsigned short* dst = outb + (size_t)2 * 4194304;
#pragma unroll
            for (int rep = 0; rep < 8; ++rep) {
                const int nn = rep * 8 + (lane >> 3);
                const int mc = (lane & 7) * 8;
                uint4 v = *(const uint4*)(Ew + nn * PADW + mc);
                const int m_g = bm0 + wm + mc;
                const int b = m_g >> 11, s0 = m_g & 2047;
                *(uint4*)(dst + (((size_t)(b * NHEAD + hh)) * DKD + nn) * SEQ + s0) = v;
            }
        }
    } else {
#pragma unroll
        for (int i = 0; i < 4; i++) {
            const int mbase = bm0 + wm + i * 16 + lq * 4;
#pragma unroll
            for (int j = 0; j < NJ; j++) {
                const int n = bn0 + wn + j * 16 + lm;
#pragma unroll
                for (int r = 0; r < 4; r++)
                    outf[(size_t)(mbase + r) * 1024 + n] = acc[i][j][r] + bias[n];
            }
        }
    }
}

// ---------------------------------------------------------------- output GEMM
// Dedicated BK=64 DOUBLE-BUFFERED kernel for the output projection (BN=64):
// 16 barrier-intervals x 16 MFMA/wave. R0-verified 8-chunk XOR swizzle; R7
// pipeline structure. LDS 49,152 B; grid 512 = 2/CU. + XCD remap.
__global__ __launch_bounds__(256) void gemm_out(const unsigned short* __restrict__ A,
                                                const unsigned short* __restrict__ Bw,
                                                float* __restrict__ outf,
                                                const float* __restrict__ bias) {
    constexpr int BN = 64;
    constexpr int TILE = (128 + BN) * 64;            // elems per buffer (A then B)
    __shared__ __align__(16) unsigned short Buf[2 * TILE];   // 49,152 B

    const int t    = threadIdx.x;
    const int lane = t & 63;
    const int w    = t >> 6;
    const int wm   = (w >> 1) * 64;
    const int wn   = (w & 1) * 32;
    const int sid  = xcd_remap(32 * gridDim.y);
    const int bm0  = (sid & 31) * 128;
    const int bn0  = (sid >> 5) * BN;
    const int lm   = lane & 15;
    const int lq   = lane >> 4;
    const int swzb = lm & 7;                 // row&7 for all frag rows

    const unsigned short* Ab = A + (size_t)bm0 * GK;
    const unsigned short* Bb = Bw + (size_t)bn0 * GK;

    f32x4 acc[4][2];
    const f32x4 Z4 = {0.f, 0.f, 0.f, 0.f};
#pragma unroll
    for (int i = 0; i < 4; i++)
#pragma unroll
        for (int j = 0; j < 2; j++) acc[i][j] = Z4;

    const int q_uni = (t & ~63);

    // stage one BK=64 tile (A[128][64] + B[64][64]) into buffer Bp
    auto STAGE = [&](unsigned short* Bp, int k0) {
        // A: 128 rows x 8 chunks = 1024 chunks, 4 per thread
#pragma unroll
        for (int i = 0; i < 4; ++i) {
            int q  = i * 256 + t;
            int r  = q >> 3;
            int gc = (q & 7) ^ (r & 7);          // global col chunk (swizzle)
            int q0 = i * 256 + q_uni;
            __builtin_amdgcn_global_load_lds(
                (const __attribute__((address_space(1))) void*)(Ab + (size_t)r * GK + k0 + gc * 8),
                (__attribute__((address_space(3))) void*)(Bp + (size_t)q0 * 8),
                16, 0, 0);
        }
        // B: 64 rows x 8 chunks = 512 chunks, 2 per thread
#pragma unroll
        for (int i = 0; i < 2; ++i) {
            int q  = i * 256 + t;
            int r  = q >> 3;
            int gc = (q & 7) ^ (r & 7);
            int q0 = i * 256 + q_uni;
            __builtin_amdgcn_global_load_lds(
                (const __attribute__((address_space(1))) void*)(Bb + (size_t)r * GK + k0 + gc * 8),
                (__attribute__((address_space(3))) void*)(Bp + 128 * 64 + (size_t)q0 * 8),
                16, 0, 0);
        }
    };

    STAGE(Buf, 0);                           // prologue: tile 0 in flight
    for (int ks = 0; ks < GK / 64; ++ks) {
        __syncthreads();                     // tile ks landed; prev reads retired
        unsigned short* Cur = Buf + (ks & 1) * TILE;
        unsigned short* Nxt = Buf + ((ks & 1) ^ 1) * TILE;
        if (ks + 1 < GK / 64) STAGE(Nxt, (ks + 1) * 64);  // async, hides under compute

#pragma unroll
        for (int kk = 0; kk < 2; ++kk) {
            const int swz = ((kk * 4 + lq) ^ swzb) * 8;   // un-swizzled col elems
            bf16x8 af[4], bf[2];
#pragma unroll
            for (int i = 0; i < 4; i++)
                af[i] = *(const bf16x8*)(Cur + (wm + i * 16 + lm) * 64 + swz);
#pragma unroll
            for (int j = 0; j < 2; j++)
                bf[j] = *(const bf16x8*)(Cur + 128 * 64 + (wn + j * 16 + lm) * 64 + swz);
#pragma unroll
            for (int i = 0; i < 4; i++)
#pragma unroll
                for (int j = 0; j < 2; j++)
                    acc[i][j] = MFMA32(af[i], bf[j], acc[i][j]);
        }
    }

    // epilogue: fp32 + bias
#pragma unroll
    for (int i = 0; i < 4; i++) {
        const int mbase = bm0 + wm + i * 16 + lq * 4;
#pragma unroll
        for (int j = 0; j < 2; j++) {
            const int n = bn0 + wn + j * 16 + lm;
#pragma unroll
            for (int r = 0; r < 4; r++)
                outf[(size_t)(mbase + r) * 1024 + n] = acc[i][j][r] + bias[n];
        }
    }
}

// ---------------------------------------------------------------- flash attention
// R7-PROVEN STRUCTURE (memory/barrier side byte-identical). 128-ROW Q TILE,
// 2x2 SPLIT: wave w = (qg = w>>1, kg = w&1) owns rows half*64 + qg*32..+31 x
// keys kg*32..+31 of each 64-key tile; two q-halves share ak/bv per staged
// byte. PV at full K=32 depth (k-permutation f(kq*8+kc*4+r) = kc*16+kq*4+r
// applied identically to P pack order and V fragment reads -> exact).
// K-loop barrier is lgkm-only. NEW (VALU diet, this round):
//  (a) P->bf16 via v_cvt_pk_bf16_f32 (RNE; 1 instr vs pack_bf2's 3 — 16/iter).
//  (b) l-row-sum via ones-MFMA: lo[h2][c] += MFMA(pa[c], ONES) on the matrix
//      pipe replaces 28 VALU adds/iter AND the epilogue shfl-reduce. Output
//      layout: lane(lm,kq) reg r = l for q = c*16+kq*4+r (replicated over lm,
//      keys of this wave); l now sums the SAME bf16-rounded P as the PV
//      numerator (rounding-consistent). Grid 512, 2 blocks/CU.
__global__ __launch_bounds__(256, 2) void attn_kernel(const unsigned short* __restrict__ Qg,
                                                      const unsigned short* __restrict__ Kg,
                                                      const unsigned short* __restrict__ Vtg,
                                                      unsigned short* __restrict__ Og) {
    __shared__ __align__(16) unsigned short KV[2][2][64 * PADW];  // 36,864 B

    const int id  = blockIdx.x;
    const int xcd = id & 7;
    const int j8  = id >> 3;                 // 0..63
    const int bh  = xcd * 4 + (j8 & 3);      // 4 heads per XCD
    const int qb  = j8 >> 2;                 // 0..15 (128-row q super-blocks)
    const unsigned short* Qp  = Qg  + ((size_t)bh * SEQ + qb * 128) * DKD;
    const unsigned short* Kp  = Kg  + (size_t)bh * SEQ * DKD;
    const unsigned short* Vtp = Vtg + (size_t)bh * DKD * SEQ;

    const int t    = threadIdx.x;
    const int lane = t & 63;
    const int w    = t >> 6;
    const int qg   = w >> 1;       // q-group (32 rows within each 64-row half)
    const int kg   = w & 1;        // key-group (32 keys of each 64-key tile)
    const int lm   = lane & 15;
    const int kq   = lane >> 4;

    const f32x4 Z4 = {0.f, 0.f, 0.f, 0.f};
    const short ONE_BF = (short)0x3F80;      // bf16 1.0
    const bf16x8 ONES = {ONE_BF, ONE_BF, ONE_BF, ONE_BF, ONE_BF, ONE_BF, ONE_BF, ONE_BF};

    // Q B-frags: two 64-row halves, this wave's 32 rows of each
    bf16x8 aq[2][2][2];            // [half][c][kk]
#pragma unroll
    for (int h2 = 0; h2 < 2; ++h2)
#pragma unroll
        for (int c = 0; c < 2; ++c)
#pragma unroll
            for (int kk = 0; kk < 2; ++kk)
                aq[h2][c][kk] = *(const bf16x8*)(Qp + (size_t)(h2 * 64 + qg * 32 + c * 16 + lm) * DKD + kk * 32 + kq * 8);

    f32x4 o[2][2][4];              // [half][q-chunk][d-chunk], partial over 32 keys
    f32x4 lo[2][2];                // [half][q-chunk] l partials via ones-MFMA
#pragma unroll
    for (int h2 = 0; h2 < 2; ++h2)
#pragma unroll
        for (int c = 0; c < 2; ++c) {
            lo[h2][c] = Z4;
#pragma unroll
            for (int dj = 0; dj < 4; ++dj) o[h2][c][dj] = Z4;
        }

    // staging: K tile [64 key][64 d], V tile [64 d][64 key]; 2 uint4/thread each
    const int sr = t >> 2, sc = (t & 3) * 16;
    uint4 kreg0, kreg1, vreg0, vreg1;
    {   // tile 0 -> buf 0
        const unsigned short* kp = Kp + (size_t)sr * DKD + sc;
        const unsigned short* vp = Vtp + (size_t)sr * SEQ + sc;
        uint4 a0 = *(const uint4*)(kp), a1 = *(const uint4*)(kp + 8);
        uint4 b0 = *(const uint4*)(vp), b1 = *(const uint4*)(vp + 8);
        uint4* dk = (uint4*)(&KV[0][0][sr * PADW + sc]); dk[0] = a0; dk[1] = a1;
        uint4* dv = (uint4*)(&KV[0][1][sr * PADW + sc]); dv[0] = b0; dv[1] = b1;
    }
    {   // prefetch tile 1
        const unsigned short* kp = Kp + (size_t)(64 + sr) * DKD + sc;
        kreg0 = *(const uint4*)(kp); kreg1 = *(const uint4*)(kp + 8);
        const unsigned short* vp = Vtp + (size_t)sr * SEQ + 64 + sc;
        vreg0 = *(const uint4*)(vp); vreg1 = *(const uint4*)(vp + 8);
    }

    for (int kt = 0; kt < 32; ++kt) {
        // lgkm-only barrier: LDS ordering only; global prefetch stays in flight
        asm volatile("s_waitcnt lgkmcnt(0)\n\ts_barrier" ::: "memory");
        const unsigned short* Kc = &KV[kt & 1][0][0];
        const unsigned short* Vc = &KV[kt & 1][1][0];

        // K A-frags for this wave's 32 keys (issued first; in-order lgkm)
        bf16x8 ak[2][2];
#pragma unroll
        for (int kc = 0; kc < 2; ++kc)
#pragma unroll
            for (int kk = 0; kk < 2; ++kk)
                ak[kc][kk] = *(const bf16x8*)(Kc + (kg * 32 + kc * 16 + lm) * PADW + kk * 32 + kq * 8);

        // write prefetched tile kt+1 -> other buf (its readers retired pre-barrier)
        if (kt + 1 < 32) {
            uint4* dk = (uint4*)(&KV[(kt + 1) & 1][0][sr * PADW + sc]);
            dk[0] = kreg0; dk[1] = kreg1;
            uint4* dv = (uint4*)(&KV[(kt + 1) & 1][1][sr * PADW + sc]);
            dv[0] = vreg0; dv[1] = vreg1;
        }
        if (kt + 2 < 32) {
            const unsigned short* kp = Kp + (size_t)((kt + 2) * 64 + sr) * DKD + sc;
            kreg0 = *(const uint4*)(kp); kreg1 = *(const uint4*)(kp + 8);
            const unsigned short* vp = Vtp + (size_t)sr * SEQ + (kt + 2) * 64 + sc;
            vreg0 = *(const uint4*)(vp); vreg1 = *(const uint4*)(vp + 8);
        }

        // V B-frags under permutation f (shared by both q-halves)
        bf16x8 bv[4];
#pragma unroll
        for (int dj = 0; dj < 4; ++dj) {
            const unsigned short* vr = Vc + (dj * 16 + lm) * PADW + kg * 32;
            u32x2 lo2 = __builtin_bit_cast(u32x2, *(const bf16x4*)(vr + kq * 4));
            u32x2 hi2 = __builtin_bit_cast(u32x2, *(const bf16x4*)(vr + 16 + kq * 4));
            u32x4 uu; uu.x = lo2.x; uu.y = lo2.y; uu.z = hi2.x; uu.w = hi2.y;
            bv[dj] = __builtin_bit_cast(bf16x8, uu);
        }

        // two independent q-halves share ak/bv: 2x work per staged byte
#pragma unroll
        for (int h2 = 0; h2 < 2; ++h2) {
            // S^T[32 keys][32 q]: s[kc][c], lane holds key kc*16+kq*4+r, q c*16+lm
            f32x4 s[2][2];
            __builtin_amdgcn_s_setprio(1);
#pragma unroll
            for (int kc = 0; kc < 2; ++kc)
#pragma unroll
                for (int c = 0; c < 2; ++c) {
                    s[kc][c] = MFMA32(ak[kc][0], aq[h2][c][0], Z4);
                    s[kc][c] = MFMA32(ak[kc][1], aq[h2][c][1], s[kc][c]);
                }
            __builtin_amdgcn_s_setprio(0);

            // p = exp2(s)
#pragma unroll
            for (int c = 0; c < 2; ++c)
#pragma unroll
                for (int kc = 0; kc < 2; ++kc)
#pragma unroll
                    for (int r = 0; r < 4; ++r) s[kc][c][r] = EXP2(s[kc][c][r]);

            // pack P under f (HW cvt_pk, RNE): element j=kc*4+r = P[q=lm][key kc*16+kq*4+r]
            bf16x8 pa[2];
#pragma unroll
            for (int c = 0; c < 2; ++c) {
                u32x4 uu;
                uu.x = cvt_pk_bf16(s[0][c][0], s[0][c][1]);
                uu.y = cvt_pk_bf16(s[0][c][2], s[0][c][3]);
                uu.z = cvt_pk_bf16(s[1][c][0], s[1][c][1]);
                uu.w = cvt_pk_bf16(s[1][c][2], s[1][c][3]);
                pa[c] = __builtin_bit_cast(bf16x8, uu);
            }

            // O += P V over this wave's 32 keys; l += P·1 via ones-MFMA
            __builtin_amdgcn_s_setprio(1);
#pragma unroll
            for (int dj = 0; dj < 4; ++dj)
#pragma unroll
                for (int c = 0; c < 2; ++c)
                    o[h2][c][dj] = MFMA32(pa[c], bv[dj], o[h2][c][dj]);
#pragma unroll
            for (int c = 0; c < 2; ++c)
                lo[h2][c] = MFMA32(pa[c], ONES, lo[h2][c]);
            __builtin_amdgcn_s_setprio(0);
        }
    }

    // ---------------- cross-wave reduction through retired KV LDS ----------
    __syncthreads();
    float* Lf = (float*)(&KV[0][0][0]);       // 9216 floats available

    // l partials straight from lo (no shfl reduce needed): lane(lm,kq) reg r
    // holds l for q = c*16 + kq*4 + r, replicated over lm -> lm==0 writes.
#pragma unroll
    for (int h2 = 0; h2 < 2; ++h2)
#pragma unroll
        for (int c = 0; c < 2; ++c)
            if (lm == 0) {
#pragma unroll
                for (int r = 0; r < 4; ++r)
                    Lf[(h2 * 4 + w) * 32 + c * 16 + kq * 4 + r] = lo[h2][c][r];
            }
    __syncthreads();

    // each thread computes linv for the q-rows it will store (rq, per half)
    const int rq = t >> 2;                    // 0..63 (row within half)
    const int dq = (t & 3) * 8;               // d offset within 32-chunk
    const int qgr = rq >> 5, qlr = rq & 31;
    float li[2];
#pragma unroll
    for (int h2 = 0; h2 < 2; ++h2) {
        float l = Lf[(h2 * 4 + qgr * 2) * 32 + qlr] + Lf[(h2 * 4 + qgr * 2 + 1) * 32 + qlr];
#if __has_builtin(__builtin_amdgcn_rcpf)
        li[h2] = __builtin_amdgcn_rcpf(l);
#else
        li[h2] = 1.0f / l;
#endif
    }
    __syncthreads();                          // l reads done before overwrite

    const int b = bh >> 4, h = bh & 15;
    // O: two passes of 32 d-columns; 256 partial rows (2 halves x 4 waves x 32)
    // x 36-float stride = 9216 floats exactly.
#pragma unroll
    for (int p = 0; p < 2; ++p) {
#pragma unroll
        for (int h2 = 0; h2 < 2; ++h2)
#pragma unroll
            for (int c = 0; c < 2; ++c)
#pragma unroll
                for (int djh = 0; djh < 2; ++djh) {
                    const int dj = 2 * p + djh;
#pragma unroll
                    for (int r = 0; r < 4; ++r)
                        Lf[((h2 * 4 + w) * 32 + c * 16 + kq * 4 + r) * 36 + djh * 16 + lm] = o[h2][c][dj][r];
                }
        __syncthreads();
#pragma unroll
        for (int h2 = 0; h2 < 2; ++h2) {
            const int rowA = ((h2 * 4 + qgr * 2) * 32 + qlr) * 36;
            const int rowB = ((h2 * 4 + qgr * 2 + 1) * 32 + qlr) * 36;
            f32x4 a0 = *(const f32x4*)(Lf + rowA + dq) + *(const f32x4*)(Lf + rowB + dq);
            f32x4 a1 = *(const f32x4*)(Lf + rowA + dq + 4) + *(const f32x4*)(Lf + rowB + dq + 4);
            uint4 outv;
            outv.x = cvt_pk_bf16(a0[0] * li[h2], a0[1] * li[h2]);
            outv.y = cvt_pk_bf16(a0[2] * li[h2], a0[3] * li[h2]);
            outv.z = cvt_pk_bf16(a1[0] * li[h2], a1[1] * li[h2]);
            outv.w = cvt_pk_bf16(a1[2] * li[h2], a1[3] * li[h2]);
            *(uint4*)(Og + (((size_t)(b * SEQ + qb * 128 + h2 * 64 + rq)) * NHEAD + h) * DKD + p * 32 + dq) = outv;
        }
        __syncthreads();
    }
}

// ---------------------------------------------------------------- launcher
extern "C" void kernel_launch(void* const* d_in, const int* in_sizes, int n_in,
                              void* d_out, int out_size, void* d_ws, size_t ws_size,
                              hipStream_t stream) {
    const float* x  = (const float*)d_in[0];
    const float* Wq = (const float*)d_in[1];
    const float* Wk = (const float*)d_in[2];
    const float* Wv = (const float*)d_in[3];
    const float* Wo = (const float*)d_in[4];
    const float* bo = (const float*)d_in[5];
    float* out = (float*)d_out;

    unsigned short* ws = (unsigned short*)d_ws;
    unsigned short* Xb   = ws;                       // [4096][1024]
    unsigned short* Wqkv = ws + 4194304;             // [3072][1024] (Wq|Wk|Wv)
    unsigned short* Wob  = ws + 7340032;             // [1024][1024]
    unsigned short* QKV  = ws + 8388608;             // Q,K:[b,h,s,d]; V:[b,h,d,s]
    unsigned short* Ob   = ws + 20971520;            // [4096][1024] = [b,s,h,d]

    cast_all<<<8192, 256, 0, stream>>>(x, Wq, Wk, Wv, Wo, Xb, Wqkv, Wob);
    gemm_bt<0, 128><<<dim3(32, 24), 256, 0, stream>>>(Xb, Wqkv, QKV, nullptr, nullptr);
    attn_kernel<<<512, 256, 0, stream>>>(QKV, QKV + 4194304, QKV + 8388608, Ob);
    gemm_out<<<dim3(32, 16), 256, 0, stream>>>(Ob, Wob, out, bo);
}